// Round 4
// baseline (599.648 us; speedup 1.0000x reference)
//
#include <hip/hip_runtime.h>

#define N_NODES 200000
#define N_EDGES 400000
#define N_GRAPHS 64
#define HDIM 128
#define INDIM 5
#define LN_EPS 1e-5f
#define LDA 140  // 70 dwords/row: 70 mod 32 = 6 -> frag reads distributed
#define NPBLK 64 // nodes per block (4 waves x 16 rows) -- R12 verified config

typedef __attribute__((ext_vector_type(8))) short short8;
typedef __attribute__((ext_vector_type(4))) float f32x4;

__device__ __forceinline__ unsigned short to_bf(float v) {
    unsigned u = __builtin_bit_cast(unsigned, v);
    return (unsigned short)((u + 0x7FFFu + ((u >> 16) & 1u)) >> 16);
}
__device__ __forceinline__ float bf_lo(unsigned w) { return __builtin_bit_cast(float, w << 16); }
__device__ __forceinline__ float bf_hi(unsigned w) { return __builtin_bit_cast(float, w & 0xFFFF0000u); }
__device__ __forceinline__ float bf2f(unsigned short h) { return __builtin_bit_cast(float, (unsigned)h << 16); }

// 1-instr RTNE f32->bf16 (same rounding as to_bf); single-value form uses low half
__device__ __forceinline__ unsigned short cvt1_bf(float v) {
    unsigned r;
    asm("v_cvt_pk_bf16_f32 %0, %1, %1" : "=v"(r) : "v"(v));
    return (unsigned short)r;
}
__device__ __forceinline__ unsigned cvt2_bf(float lo, float hi) {
    unsigned r;
    asm("v_cvt_pk_bf16_f32 %0, %1, %2" : "=v"(r) : "v"(lo), "v"(hi));
    return r;
}

// ---- gather macros: literal indices only, no staging arrays (R1/R3 scratch lessons),
// no token pasting (R2 lesson). accs is float[32], compile-time-indexed everywhere.
#define GLOAD(q0, q1, q2, q3, srcrow)                                       \
    {                                                                       \
        const uint4* xs_ = (const uint4*)(xin + (size_t)(srcrow)*128 + c0); \
        q0 = xs_[0]; q1 = xs_[1]; q2 = xs_[2]; q3 = xs_[3];                 \
    }

// one dword wd = channel pair (2*i0, 2*i0+1): accs += relu(x + eb + a*ew)
#define GP2(wd, i0)                                                          \
    {                                                                        \
        float4 wb_ = ep[i0]; /* {ew0,ew1,eb0,eb1} broadcast b128 */          \
        accs[2 * (i0)] += fmaxf(fmaf(av_, wb_.x, bf_lo(wd) + wb_.z), 0.f);   \
        accs[2 * (i0) + 1] += fmaxf(fmaf(av_, wb_.y, bf_hi(wd) + wb_.w), 0.f); \
    }

#define GPROC(q0, q1, q2, q3, a_)                                 \
    {                                                             \
        float av_ = (a_);                                         \
        GP2(q0.x, 0) GP2(q0.y, 1) GP2(q0.z, 2) GP2(q0.w, 3)       \
        GP2(q1.x, 4) GP2(q1.y, 5) GP2(q1.z, 6) GP2(q1.w, 7)       \
        GP2(q2.x, 8) GP2(q2.y, 9) GP2(q2.z, 10) GP2(q2.w, 11)     \
        GP2(q3.x, 12) GP2(q3.y, 13) GP2(q3.z, 14) GP2(q3.w, 15)   \
    }

#define GI2(wd, i0)                       \
    {                                     \
        accs[2 * (i0)] = bf_lo(wd);       \
        accs[2 * (i0) + 1] = bf_hi(wd);   \
    }

#define GINIT(q0, q1, q2, q3)                                     \
    {                                                             \
        GI2(q0.x, 0) GI2(q0.y, 1) GI2(q0.z, 2) GI2(q0.w, 3)       \
        GI2(q1.x, 4) GI2(q1.y, 5) GI2(q1.z, 6) GI2(q1.w, 7)       \
        GI2(q2.x, 8) GI2(q2.y, 9) GI2(q2.z, 10) GI2(q2.w, 11)     \
        GI2(q3.x, 12) GI2(q3.y, 13) GI2(q3.z, 14) GI2(q3.w, 15)   \
    }

// ---------------- CSR build ----------------

__global__ void hist_kernel(const int* __restrict__ ei, int* __restrict__ deg) {
    int e = blockIdx.x * blockDim.x + threadIdx.x;
    if (e < N_EDGES) atomicAdd(&deg[ei[N_EDGES + e]], 1);
}

#define SCAN_CHUNK 1024
#define SCAN_BLOCKS ((N_NODES + SCAN_CHUNK - 1) / SCAN_CHUNK)  // 196

// also zeroes pool+cnt (block 0) -- saves a memset range
__global__ __launch_bounds__(256) void scan_phaseA(const int* __restrict__ deg, int* __restrict__ bsums,
                                                   int* __restrict__ poolz) {
    if (blockIdx.x == 0) {
        for (int i = threadIdx.x; i < N_GRAPHS * HDIM + N_GRAPHS; i += 256) poolz[i] = 0;
    }
    __shared__ int red[256];
    int t = threadIdx.x;
    int base = blockIdx.x * SCAN_CHUNK + t * 4;
    int s = 0;
#pragma unroll
    for (int k = 0; k < 4; ++k) {
        int i = base + k;
        s += (i < N_NODES) ? deg[i] : 0;
    }
    red[t] = s;
    __syncthreads();
    for (int off = 128; off; off >>= 1) {
        if (t < off) red[t] += red[t + off];
        __syncthreads();
    }
    if (t == 0) bsums[blockIdx.x] = red[0];
}

__global__ __launch_bounds__(256) void scan_phaseB(int* __restrict__ bsums, int* __restrict__ row_ptr) {
    __shared__ int s[256];
    int t = threadIdx.x;
    int v = (t < SCAN_BLOCKS) ? bsums[t] : 0;
    s[t] = v;
    __syncthreads();
    for (int off = 1; off < 256; off <<= 1) {
        int add = (t >= off) ? s[t - off] : 0;
        __syncthreads();
        s[t] += add;
        __syncthreads();
    }
    if (t < SCAN_BLOCKS) bsums[t] = s[t] - v;  // exclusive
    if (t == SCAN_BLOCKS - 1) row_ptr[N_NODES] = s[t];
}

// also zeroes cursor -- saves a memset range
__global__ __launch_bounds__(256) void scan_phaseC(const int* __restrict__ deg,
                                                   const int* __restrict__ bsums,
                                                   int* __restrict__ row_ptr,
                                                   int* __restrict__ cursor) {
    __shared__ int ts[256];
    int t = threadIdx.x;
    int base = blockIdx.x * SCAN_CHUNK + t * 4;
    int v[4];
    int s = 0;
#pragma unroll
    for (int k = 0; k < 4; ++k) {
        int i = base + k;
        v[k] = (i < N_NODES) ? deg[i] : 0;
        s += v[k];
    }
    ts[t] = s;
    __syncthreads();
    for (int off = 1; off < 256; off <<= 1) {
        int add = (t >= off) ? ts[t - off] : 0;
        __syncthreads();
        ts[t] += add;
        __syncthreads();
    }
    int run = bsums[blockIdx.x] + ts[t] - s;
#pragma unroll
    for (int k = 0; k < 4; ++k) {
        int i = base + k;
        if (i < N_NODES) { row_ptr[i] = run; cursor[i] = 0; }
        run += v[k];
    }
}

// ---------------- Fused scatter (CSR fill) + weight packing ----------------
#define SCATTER_BLOCKS ((N_EDGES + 255) / 256)  // 1563

__global__ void scatter_pack(const int* __restrict__ ei, const float* __restrict__ ea,
                             const int* __restrict__ row_ptr, int* __restrict__ cursor,
                             int2* __restrict__ csr,
                             const float* __restrict__ s0, short* __restrict__ d0,
                             const float* __restrict__ s1, short* __restrict__ d1,
                             const float* __restrict__ s2, short* __restrict__ d2,
                             const float* __restrict__ s3, short* __restrict__ d3,
                             const float* __restrict__ s4, short* __restrict__ d4,
                             const float* __restrict__ s5, short* __restrict__ d5) {
    int b = blockIdx.x;
    if (b < SCATTER_BLOCKS) {
        int e = b * 256 + threadIdx.x;
        if (e >= N_EDGES) return;
        int d = ei[N_EDGES + e];
        int pos = atomicAdd(&cursor[d], 1);
        csr[row_ptr[d] + pos] = make_int2(ei[e], __float_as_int(ea[e]));
        return;
    }
    b -= SCATTER_BLOCKS;
    const float* W;
    short* D;
    int din, KP, b0;
    if (b < 16)       { W = s0; D = d0; din = 5;   KP = 32;  b0 = 0; }
    else if (b < 80)  { W = s1; D = d1; din = 128; KP = 128; b0 = 16; }
    else if (b < 144) { W = s2; D = d2; din = 128; KP = 128; b0 = 80; }
    else if (b < 208) { W = s3; D = d3; din = 128; KP = 128; b0 = 144; }
    else if (b < 272) { W = s4; D = d4; din = 128; KP = 128; b0 = 208; }
    else              { W = s5; D = d5; din = 128; KP = 128; b0 = 272; }
    int idx = (b - b0) * 256 + threadIdx.x;
    if (idx >= KP * 128) return;
    int j = idx & 7;
    int lane = (idx >> 3) & 63;
    int rest = idx >> 9;
    int KS = KP >> 5;
    int kstep = rest % KS;
    int tile = rest / KS;
    int k = kstep * 32 + ((lane >> 4) * 8) + j;
    int n = tile * 16 + (lane & 15);
    float v = (k < din) ? W[k * 128 + n] : 0.f;
    D[idx] = (short)to_bf(v);
}

// ---------------- shared MFMA MLP + reg-LN + ReLU (+pool) tail ----------------
template <int KP1, bool POOL>
__device__ __forceinline__ void mlp_tail(
    unsigned short* A16, const int* bidx, int tid, int node0,
    const short* __restrict__ w1h, const float* __restrict__ b1,
    const short* __restrict__ w2h, const float* __restrict__ b2,
    const float* __restrict__ g, const float* __restrict__ bt,
    unsigned short* __restrict__ xout, float* __restrict__ pool, int* __restrict__ cnt) {
    int wv = tid >> 6, lane = tid & 63;
    int mrow = lane & 15, q = lane >> 4;
    int arow = wv * 16 + mrow;

    const short8* w1p = (const short8*)w1h;
    const short8* w2p = (const short8*)w2h;

    f32x4 acc2[8];
#pragma unroll
    for (int t = 0; t < 8; ++t) acc2[t] = (f32x4){0.f, 0.f, 0.f, 0.f};
    constexpr int KS1 = KP1 / 32;
#pragma unroll
    for (int ks = 0; ks < KS1; ++ks) {
        short8 bh[8];
#pragma unroll
        for (int t = 0; t < 8; ++t) bh[t] = w1p[((size_t)t * KS1 + ks) * 64 + lane];
        short8 ah = *(const short8*)&A16[arow * LDA + ks * 32 + q * 8];
#pragma unroll
        for (int t = 0; t < 8; ++t)
            acc2[t] = __builtin_amdgcn_mfma_f32_16x16x32_bf16(ah, bh[t], acc2[t], 0, 0, 0);
    }
    // t1 = relu(acc + b1) -> bf16 A (wave-local rows)
    {
        float b1v[8];
#pragma unroll
        for (int t = 0; t < 8; ++t) b1v[t] = b1[t * 16 + mrow];
#pragma unroll
        for (int t = 0; t < 8; ++t)
#pragma unroll
            for (int r = 0; r < 4; ++r) {
                int rrow = wv * 16 + q * 4 + r;
                int col = t * 16 + mrow;
                A16[rrow * LDA + col] = cvt1_bf(fmaxf(acc2[t][r] + b1v[t], 0.f));
            }
    }

    // GEMM2 (K = 128); A reads wave-local
#pragma unroll
    for (int t = 0; t < 8; ++t) acc2[t] = (f32x4){0.f, 0.f, 0.f, 0.f};
#pragma unroll
    for (int ks = 0; ks < 4; ++ks) {
        short8 bh[8];
#pragma unroll
        for (int t = 0; t < 8; ++t) bh[t] = w2p[((size_t)t * 4 + ks) * 64 + lane];
        short8 ah = *(const short8*)&A16[arow * LDA + ks * 32 + q * 8];
#pragma unroll
        for (int t = 0; t < 8; ++t)
            acc2[t] = __builtin_amdgcn_mfma_f32_16x16x32_bf16(ah, bh[t], acc2[t], 0, 0, 0);
    }

    // ---- LayerNorm in registers (rows live in 16-lane groups) ----
    float s4[4] = {0.f, 0.f, 0.f, 0.f}, q4[4] = {0.f, 0.f, 0.f, 0.f};
    {
        float b2v[8];
#pragma unroll
        for (int t = 0; t < 8; ++t) b2v[t] = b2[t * 16 + mrow];
#pragma unroll
        for (int t = 0; t < 8; ++t)
#pragma unroll
            for (int r = 0; r < 4; ++r) {
                float v = acc2[t][r] + b2v[t];
                acc2[t][r] = v;
                s4[r] += v;
                q4[r] += v * v;
            }
    }
#pragma unroll
    for (int m = 1; m <= 8; m <<= 1) {
#pragma unroll
        for (int r = 0; r < 4; ++r) {
            s4[r] += __shfl_xor(s4[r], m, 64);
            q4[r] += __shfl_xor(q4[r], m, 64);
        }
    }
    float mu[4], inv[4];
#pragma unroll
    for (int r = 0; r < 4; ++r) {
        mu[r] = s4[r] * (1.f / HDIM);
        float var = q4[r] * (1.f / HDIM) - mu[r] * mu[r];
        inv[r] = rsqrtf(var + LN_EPS);
    }
    float gv[8], btv[8];
#pragma unroll
    for (int t = 0; t < 8; ++t) {
        gv[t] = g[t * 16 + mrow];
        btv[t] = bt[t * 16 + mrow];
    }

    // LN result -> LDS (wave-local row writes; no pre-barrier needed)
#pragma unroll
    for (int t = 0; t < 8; ++t)
#pragma unroll
        for (int r = 0; r < 4; ++r) {
            int rrow = wv * 16 + q * 4 + r;
            int col = t * 16 + mrow;
            float o = fmaxf((acc2[t][r] - mu[r]) * inv[r] * gv[t] + btv[t], 0.f);
            A16[rrow * LDA + col] = cvt1_bf(o);
        }
    __syncthreads();  // epilogue reads all rows (cross-wave)

    if (!POOL) {
        // coalesced copy-out: wave inst covers 256 contiguous bytes (4 full lines)
        unsigned* xo = (unsigned*)xout;
#pragma unroll
        for (int i = 0; i < 16; ++i) {
            int idx = tid + 256 * i;       // 4096 = 64 rows x 64 words
            int row = idx >> 6, w = idx & 63;
            xo[(size_t)(node0 + row) * 64 + w] = ((const unsigned*)&A16[row * LDA])[w];
        }
    } else {
        if (tid < 128) {
            int col = tid;
            float accp = 0.f;
            int cur = bidx[0];
            for (int r = 0; r < NPBLK; ++r) {
                int gi = bidx[r];
                if (gi != cur) {
                    unsafeAtomicAdd(&pool[cur * HDIM + col], accp);
                    accp = 0.f;
                    cur = gi;
                }
                accp += bf2f(A16[r * LDA + col]);
            }
            unsafeAtomicAdd(&pool[cur * HDIM + col], accp);
        } else if (tid == 255) {
            int cur = bidx[0], c = 0;
            for (int r = 0; r < NPBLK; ++r) {
                if (bidx[r] != cur) {
                    atomicAdd(&cnt[cur], c);
                    c = 0;
                    cur = bidx[r];
                }
                ++c;
            }
            atomicAdd(&cnt[cur], c);
        }
    }
}

// ---------------- din=128 fused layer: gather pipeline + MFMA tail ----------------
// waves_per_eu pinned to (4,4): allocator may use the full 128-VGPR budget for the
// 2-edge pipeline (~90 live). R3 evidence: min-only bound -> allocator targeted
// 8 waves/EU, capped at 64 VGPR, spilled ~200MB/dispatch to scratch.
template <bool POOL>
__global__ __attribute__((amdgpu_waves_per_eu(4, 4))) __launch_bounds__(256)
void layerH_fused(
    const unsigned short* __restrict__ xin, const int* __restrict__ row_ptr,
    const int2* __restrict__ csr,
    const float* __restrict__ ew, const float* __restrict__ eb,
    const short* __restrict__ w1h, const float* __restrict__ b1,
    const short* __restrict__ w2h, const float* __restrict__ b2,
    const float* __restrict__ g, const float* __restrict__ bt,
    unsigned short* __restrict__ xout,
    const int* __restrict__ batch, float* __restrict__ pool, int* __restrict__ cnt) {
    __shared__ __align__(16) unsigned short A16[NPBLK * LDA];
    __shared__ int bidx[NPBLK];
    __shared__ __align__(16) float eweb4[4 * 17 * 4];  // padded {ew,ew,eb,eb} float4 table

    int tid = threadIdx.x;
    int node0 = blockIdx.x * NPBLK;

    // stage padded edge-encoder table: qt groups at float4 stride 17 (conflict-free broadcasts)
    if (tid < 64) {
        int qq = tid >> 4, ii = tid & 15, c = qq * 32 + ii * 2;
        ((float4*)eweb4)[qq * 17 + ii] = make_float4(ew[c], ew[c + 1], eb[c], eb[c + 1]);
    }
    if (POOL && tid >= 64 && tid < 128) bidx[tid - 64] = batch[node0 + tid - 64];

    // thread = (row, 32-channel quarter)
    int row = tid >> 2, qt = tid & 3, c0 = qt * 32;
    int node = node0 + row;

    // own-row load + 2-edge pipeline preamble issued before the barrier (in flight across it)
    const uint4* xn = (const uint4*)(xin + (size_t)node * 128 + c0);
    uint4 o0 = xn[0], o1 = xn[1], o2 = xn[2], o3 = xn[3];
    int beg = row_ptr[node], end = row_ptr[node + 1];

    uint4 va0, va1, va2, va3, vb0, vb1, vb2, vb3;
    float aA = 0.f, aB = 0.f;
    if (beg < end) {
        int2 r = csr[beg];
        aA = __int_as_float(r.y);
        GLOAD(va0, va1, va2, va3, r.x);
    }
    if (beg + 1 < end) {
        int2 r = csr[beg + 1];
        aB = __int_as_float(r.y);
        GLOAD(vb0, vb1, vb2, vb3, r.x);
    }
    __syncthreads();  // eweb4 ready
    const float4* ep = ((const float4*)eweb4) + qt * 17;

    float accs[32];
    GINIT(o0, o1, o2, o3);

    // software-pipelined gather: consume edge e while e+1 in flight; refill with e+2; etc.
    int e = beg;
    while (e + 3 < end) {
        GPROC(va0, va1, va2, va3, aA);
        {
            int2 r = csr[e + 2];
            aA = __int_as_float(r.y);
            GLOAD(va0, va1, va2, va3, r.x);
        }
        GPROC(vb0, vb1, vb2, vb3, aB);
        {
            int2 r = csr[e + 3];
            aB = __int_as_float(r.y);
            GLOAD(vb0, vb1, vb2, vb3, r.x);
        }
        e += 2;
    }
    // drain: at most 3 edges remain
    if (e < end) GPROC(va0, va1, va2, va3, aA);
    if (e + 1 < end) GPROC(vb0, vb1, vb2, vb3, aB);
    if (e + 2 < end) {
        int2 r = csr[e + 2];
        GLOAD(va0, va1, va2, va3, r.x);
        GPROC(va0, va1, va2, va3, __int_as_float(r.y));
    }

    // packed cvt + uint2 stores (2-way bank aliasing only = free)
    uint2* Ar2 = (uint2*)&A16[row * LDA + c0];
#pragma unroll
    for (int k = 0; k < 8; ++k) {
        Ar2[k] = make_uint2(cvt2_bf(accs[4 * k], accs[4 * k + 1]),
                            cvt2_bf(accs[4 * k + 2], accs[4 * k + 3]));
    }
    // no barrier: rows [16wv,16wv+16) are written and read by the same wave

    mlp_tail<128, POOL>(A16, bidx, tid, node0, w1h, b1, w2h, b2, g, bt, xout, pool, cnt);
}

// ---------------- din=5 first layer (unchanged structure; never pools) ----------------
__global__ __launch_bounds__(256, 4) void layer0_fused(
    const float* __restrict__ xinf, const int* __restrict__ row_ptr,
    const int2* __restrict__ csr,
    const float* __restrict__ ew, const float* __restrict__ eb,
    const short* __restrict__ w1h, const float* __restrict__ b1,
    const short* __restrict__ w2h, const float* __restrict__ b2,
    const float* __restrict__ g, const float* __restrict__ bt,
    unsigned short* __restrict__ xout) {
    __shared__ __align__(16) unsigned short A16[NPBLK * LDA];
    __shared__ float part[NPBLK][4][INDIM];

    int tid = threadIdx.x;
    int node0 = blockIdx.x * NPBLK;

    // 4 threads/row split the edge list; register partials
    int row = tid >> 2, qt = tid & 3;
    int node = node0 + row;
    {
        float w[INDIM], b[INDIM], acc[INDIM];
#pragma unroll
        for (int j = 0; j < INDIM; ++j) {
            w[j] = ew[j];
            b[j] = eb[j];
            acc[j] = 0.f;
        }
        int beg = row_ptr[node], end = row_ptr[node + 1];
        int2 r;
        if (beg + qt < end) r = csr[beg + qt];
        for (int e = beg + qt; e < end; e += 4) {
            int2 rn = (e + 4 < end) ? csr[e + 4] : r;
            float a = __int_as_float(r.y);
#pragma unroll
            for (int j = 0; j < INDIM; ++j)
                acc[j] += fmaxf(fmaf(a, w[j], xinf[r.x * INDIM + j] + b[j]), 0.f);
            r = rn;
        }
#pragma unroll
        for (int j = 0; j < INDIM; ++j) part[row][qt][j] = acc[j];
    }
    __syncthreads();
    if (tid < NPBLK) {
#pragma unroll
        for (int j = 0; j < INDIM; ++j) {
            float v = xinf[(node0 + tid) * INDIM + j] + part[tid][0][j] + part[tid][1][j] +
                      part[tid][2][j] + part[tid][3][j];
            A16[tid * LDA + j] = cvt1_bf(v);
        }
#pragma unroll
        for (int j = INDIM; j < 32; ++j) A16[tid * LDA + j] = 0;
    }
    __syncthreads();  // rows written by tid<64 -> cross-wave

    mlp_tail<32, false>(A16, nullptr, tid, node0, w1h, b1, w2h, b2, g, bt, xout, nullptr, nullptr);
}

__global__ void pool_final(const float* __restrict__ pool, const int* __restrict__ cnt,
                           float* __restrict__ out) {
    int g = blockIdx.x, j = threadIdx.x;
    float add = pool[g * HDIM + j];
    float c = (float)max(cnt[g], 1);
    out[g * (2 * HDIM) + j] = add / c;
    out[g * (2 * HDIM) + HDIM + j] = add;
}

extern "C" void kernel_launch(void* const* d_in, const int* in_sizes, int n_in,
                              void* d_out, int out_size, void* d_ws, size_t ws_size,
                              hipStream_t stream) {
    const float* x_in = (const float*)d_in[0];
    const int* ei = (const int*)d_in[1];
    const float* ea = (const float*)d_in[2];
    const int* batch = (const int*)d_in[3];
    const float* P[24];
    for (int i = 0; i < 24; ++i) P[i] = (const float*)d_in[4 + i];
    // per layer l (base 8l): 0=ew 1=eb 2=w1 3=b1 4=w2 5=b2 6=g 7=bt

    unsigned short* x_a = (unsigned short*)d_ws;                 // N*128 bf16
    unsigned short* x_b = x_a + (size_t)N_NODES * HDIM;          // N*128 bf16
    float* pool = (float*)(x_b + (size_t)N_NODES * HDIM);        // G*128 (zeroed in scanA)
    int* cnt = (int*)(pool + N_GRAPHS * HDIM);                   // G    (zeroed in scanA)
    int* deg = cnt + N_GRAPHS;                                   // N    (memset)
    int* cursor = deg + N_NODES;                                 // N    (zeroed in scanC)
    int* row_ptr = cursor + N_NODES;                             // N+1
    int* bsums = row_ptr + N_NODES + 1;                          // pad 256 (keeps int2 8B-aligned)
    int2* csr = (int2*)(bsums + 256);                            // E (packed {src, val})
    short* wp = (short*)(((uintptr_t)(csr + N_EDGES) + 15) & ~(uintptr_t)15);
    float* out = (float*)d_out;

    short *w1h[3], *w2h[3];
    for (int l = 0; l < 3; ++l) {
        w1h[l] = wp + (size_t)l * 32768;
        w2h[l] = w1h[l] + 16384;
    }

    // ---- memset: deg only (pool/cnt zeroed in scanA, cursor in scanC) ----
    hipMemsetAsync(deg, 0, N_NODES * sizeof(int), stream);

    // ---- CSR build ----
    hist_kernel<<<(N_EDGES + 255) / 256, 256, 0, stream>>>(ei, deg);
    scan_phaseA<<<SCAN_BLOCKS, 256, 0, stream>>>(deg, bsums, (int*)pool);
    scan_phaseB<<<1, 256, 0, stream>>>(bsums, row_ptr);
    scan_phaseC<<<SCAN_BLOCKS, 256, 0, stream>>>(deg, bsums, row_ptr, cursor);

    // ---- fused scatter + weight packing (1563 + 336 blocks) ----
    scatter_pack<<<SCATTER_BLOCKS + 336, 256, 0, stream>>>(
        ei, ea, row_ptr, cursor, csr,
        P[2], w1h[0], P[4], w2h[0],
        P[10], w1h[1], P[12], w2h[1],
        P[18], w1h[2], P[20], w2h[2]);

    // ---- fused layers ----
    layer0_fused<<<N_NODES / NPBLK, 256, 0, stream>>>(
        x_in, row_ptr, csr, P[0], P[1],
        w1h[0], P[3], w2h[0], P[5], P[6], P[7], x_a);
    layerH_fused<false><<<N_NODES / NPBLK, 256, 0, stream>>>(
        x_a, row_ptr, csr, P[8], P[9],
        w1h[1], P[11], w2h[1], P[13], P[14], P[15], x_b, nullptr, nullptr, nullptr);
    layerH_fused<true><<<N_NODES / NPBLK, 256, 0, stream>>>(
        x_b, row_ptr, csr, P[16], P[17],
        w1h[2], P[19], w2h[2], P[21], P[22], P[23], nullptr, batch, pool, cnt);

    pool_final<<<N_GRAPHS, HDIM, 0, stream>>>(pool, cnt, out);
}

// Round 5
// 391.469 us; speedup vs baseline: 1.5318x; 1.5318x over previous
//
#include <hip/hip_runtime.h>

#define N_NODES 200000
#define N_EDGES 400000
#define N_GRAPHS 64
#define HDIM 128
#define INDIM 5
#define LN_EPS 1e-5f
#define LDA 140  // 70 dwords/row: 70 mod 32 = 6 -> frag reads distributed
#define NPBLK 64 // nodes per block (8 waves x 8 rows gather; 64 rows MFMA)
#define BTH 512  // block threads: 8 threads/row -> per-thread state fits 64 VGPRs (R3/R4 lesson)

typedef __attribute__((ext_vector_type(8))) short short8;
typedef __attribute__((ext_vector_type(4))) float f32x4;

__device__ __forceinline__ unsigned short to_bf(float v) {
    unsigned u = __builtin_bit_cast(unsigned, v);
    return (unsigned short)((u + 0x7FFFu + ((u >> 16) & 1u)) >> 16);
}
__device__ __forceinline__ float bf_lo(unsigned w) { return __builtin_bit_cast(float, w << 16); }
__device__ __forceinline__ float bf_hi(unsigned w) { return __builtin_bit_cast(float, w & 0xFFFF0000u); }
__device__ __forceinline__ float bf2f(unsigned short h) { return __builtin_bit_cast(float, (unsigned)h << 16); }

// 1-instr RTNE f32->bf16 (same rounding as to_bf)
__device__ __forceinline__ unsigned short cvt1_bf(float v) {
    unsigned r;
    asm("v_cvt_pk_bf16_f32 %0, %1, %1" : "=v"(r) : "v"(v));
    return (unsigned short)r;
}
__device__ __forceinline__ unsigned cvt2_bf(float lo, float hi) {
    unsigned r;
    asm("v_cvt_pk_bf16_f32 %0, %1, %2" : "=v"(r) : "v"(lo), "v"(hi));
    return r;
}

// ---- gather macros: 16 channels/thread (8 dwords = 2 uint4). Literal indices only,
// no staging arrays, no pointer-passed locals (R1/R3 scratch lessons), no token
// pasting (R2 lesson).
#define GLOAD(p0, p1, srcrow)                                               \
    {                                                                       \
        const uint4* xs_ = (const uint4*)(xin + (size_t)(srcrow)*128 + c0); \
        p0 = xs_[0];                                                        \
        p1 = xs_[1];                                                        \
    }

// one dword wd = channel pair (2*i0, 2*i0+1): accs += relu(x + eb + a*ew)
#define GP2(wd, i0)                                                            \
    {                                                                          \
        float4 wb_ = ep[i0]; /* {ew0,ew1,eb0,eb1} broadcast b128 */            \
        accs[2 * (i0)] += fmaxf(fmaf(av_, wb_.x, bf_lo(wd) + wb_.z), 0.f);     \
        accs[2 * (i0) + 1] += fmaxf(fmaf(av_, wb_.y, bf_hi(wd) + wb_.w), 0.f); \
    }

#define GPROC(p0, p1, a_)                                   \
    {                                                       \
        float av_ = (a_);                                   \
        GP2(p0.x, 0) GP2(p0.y, 1) GP2(p0.z, 2) GP2(p0.w, 3) \
        GP2(p1.x, 4) GP2(p1.y, 5) GP2(p1.z, 6) GP2(p1.w, 7) \
    }

#define GI2(wd, i0)                     \
    {                                   \
        accs[2 * (i0)] = bf_lo(wd);     \
        accs[2 * (i0) + 1] = bf_hi(wd); \
    }

#define GINIT(p0, p1)                                       \
    {                                                       \
        GI2(p0.x, 0) GI2(p0.y, 1) GI2(p0.z, 2) GI2(p0.w, 3) \
        GI2(p1.x, 4) GI2(p1.y, 5) GI2(p1.z, 6) GI2(p1.w, 7) \
    }

// ---------------- CSR build ----------------

__global__ void hist_kernel(const int* __restrict__ ei, int* __restrict__ deg) {
    int e = blockIdx.x * blockDim.x + threadIdx.x;
    if (e < N_EDGES) atomicAdd(&deg[ei[N_EDGES + e]], 1);
}

#define SCAN_CHUNK 1024
#define SCAN_BLOCKS ((N_NODES + SCAN_CHUNK - 1) / SCAN_CHUNK)  // 196

__global__ __launch_bounds__(256) void scan_phaseA(const int* __restrict__ deg, int* __restrict__ bsums,
                                                   int* __restrict__ poolz) {
    if (blockIdx.x == 0) {
        for (int i = threadIdx.x; i < N_GRAPHS * HDIM + N_GRAPHS; i += 256) poolz[i] = 0;
    }
    __shared__ int red[256];
    int t = threadIdx.x;
    int base = blockIdx.x * SCAN_CHUNK + t * 4;
    int s = 0;
#pragma unroll
    for (int k = 0; k < 4; ++k) {
        int i = base + k;
        s += (i < N_NODES) ? deg[i] : 0;
    }
    red[t] = s;
    __syncthreads();
    for (int off = 128; off; off >>= 1) {
        if (t < off) red[t] += red[t + off];
        __syncthreads();
    }
    if (t == 0) bsums[blockIdx.x] = red[0];
}

__global__ __launch_bounds__(256) void scan_phaseB(int* __restrict__ bsums, int* __restrict__ row_ptr) {
    __shared__ int s[256];
    int t = threadIdx.x;
    int v = (t < SCAN_BLOCKS) ? bsums[t] : 0;
    s[t] = v;
    __syncthreads();
    for (int off = 1; off < 256; off <<= 1) {
        int add = (t >= off) ? s[t - off] : 0;
        __syncthreads();
        s[t] += add;
        __syncthreads();
    }
    if (t < SCAN_BLOCKS) bsums[t] = s[t] - v;  // exclusive
    if (t == SCAN_BLOCKS - 1) row_ptr[N_NODES] = s[t];
}

__global__ __launch_bounds__(256) void scan_phaseC(const int* __restrict__ deg,
                                                   const int* __restrict__ bsums,
                                                   int* __restrict__ row_ptr,
                                                   int* __restrict__ cursor) {
    __shared__ int ts[256];
    int t = threadIdx.x;
    int base = blockIdx.x * SCAN_CHUNK + t * 4;
    int v[4];
    int s = 0;
#pragma unroll
    for (int k = 0; k < 4; ++k) {
        int i = base + k;
        v[k] = (i < N_NODES) ? deg[i] : 0;
        s += v[k];
    }
    ts[t] = s;
    __syncthreads();
    for (int off = 1; off < 256; off <<= 1) {
        int add = (t >= off) ? ts[t - off] : 0;
        __syncthreads();
        ts[t] += add;
        __syncthreads();
    }
    int run = bsums[blockIdx.x] + ts[t] - s;
#pragma unroll
    for (int k = 0; k < 4; ++k) {
        int i = base + k;
        if (i < N_NODES) { row_ptr[i] = run; cursor[i] = 0; }
        run += v[k];
    }
}

// ---------------- Fused scatter (CSR fill) + weight packing ----------------
#define SCATTER_BLOCKS ((N_EDGES + 255) / 256)  // 1563

__global__ void scatter_pack(const int* __restrict__ ei, const float* __restrict__ ea,
                             const int* __restrict__ row_ptr, int* __restrict__ cursor,
                             int2* __restrict__ csr,
                             const float* __restrict__ s0, short* __restrict__ d0,
                             const float* __restrict__ s1, short* __restrict__ d1,
                             const float* __restrict__ s2, short* __restrict__ d2,
                             const float* __restrict__ s3, short* __restrict__ d3,
                             const float* __restrict__ s4, short* __restrict__ d4,
                             const float* __restrict__ s5, short* __restrict__ d5) {
    int b = blockIdx.x;
    if (b < SCATTER_BLOCKS) {
        int e = b * 256 + threadIdx.x;
        if (e >= N_EDGES) return;
        int d = ei[N_EDGES + e];
        int pos = atomicAdd(&cursor[d], 1);
        csr[row_ptr[d] + pos] = make_int2(ei[e], __float_as_int(ea[e]));
        return;
    }
    b -= SCATTER_BLOCKS;
    const float* W;
    short* D;
    int din, KP, b0;
    if (b < 16)       { W = s0; D = d0; din = 5;   KP = 32;  b0 = 0; }
    else if (b < 80)  { W = s1; D = d1; din = 128; KP = 128; b0 = 16; }
    else if (b < 144) { W = s2; D = d2; din = 128; KP = 128; b0 = 80; }
    else if (b < 208) { W = s3; D = d3; din = 128; KP = 128; b0 = 144; }
    else if (b < 272) { W = s4; D = d4; din = 128; KP = 128; b0 = 208; }
    else              { W = s5; D = d5; din = 128; KP = 128; b0 = 272; }
    int idx = (b - b0) * 256 + threadIdx.x;
    if (idx >= KP * 128) return;
    int j = idx & 7;
    int lane = (idx >> 3) & 63;
    int rest = idx >> 9;
    int KS = KP >> 5;
    int kstep = rest % KS;
    int tile = rest / KS;
    int k = kstep * 32 + ((lane >> 4) * 8) + j;
    int n = tile * 16 + (lane & 15);
    float v = (k < din) ? W[k * 128 + n] : 0.f;
    D[idx] = (short)to_bf(v);
}

// ---------------- shared 8-wave MFMA MLP + reg-LN + ReLU (+pool) tail ----------------
// wave wv: row-group (wv&3) = rows [16*(wv&3), +16), column-half (wv>>2) = tiles
// [4*half, 4*half+4). LN row-sums combined across halves via sP/qP LDS partials.
template <int KP1, bool POOL>
__device__ __forceinline__ void mlp_tail8(
    unsigned short* A16, const int* bidx, float* sP, float* qP, int tid, int node0,
    const short* __restrict__ w1h, const float* __restrict__ b1,
    const short* __restrict__ w2h, const float* __restrict__ b2,
    const float* __restrict__ g, const float* __restrict__ bt,
    unsigned short* __restrict__ xout, float* __restrict__ pool, int* __restrict__ cnt) {
    int wv = tid >> 6, lane = tid & 63;
    int wg = wv & 3, half = wv >> 2;
    int mrow = lane & 15, q = lane >> 4;
    int arow = wg * 16 + mrow;

    const short8* w1p = (const short8*)w1h;
    const short8* w2p = (const short8*)w2h;

    f32x4 acc2[4];
#pragma unroll
    for (int t = 0; t < 4; ++t) acc2[t] = (f32x4){0.f, 0.f, 0.f, 0.f};
    constexpr int KS1 = KP1 / 32;
#pragma unroll
    for (int ks = 0; ks < KS1; ++ks) {
        short8 bh[4];
#pragma unroll
        for (int t = 0; t < 4; ++t) bh[t] = w1p[((size_t)(half * 4 + t) * KS1 + ks) * 64 + lane];
        short8 ah = *(const short8*)&A16[arow * LDA + ks * 32 + q * 8];
#pragma unroll
        for (int t = 0; t < 4; ++t)
            acc2[t] = __builtin_amdgcn_mfma_f32_16x16x32_bf16(ah, bh[t], acc2[t], 0, 0, 0);
    }
    __syncthreads();  // all waves done reading layer-A before t1 overwrites rows
    // t1 = relu(acc + b1) -> bf16 A (this wave's column half of its row group)
    {
        float b1v[4];
#pragma unroll
        for (int t = 0; t < 4; ++t) b1v[t] = b1[(half * 4 + t) * 16 + mrow];
#pragma unroll
        for (int t = 0; t < 4; ++t)
#pragma unroll
            for (int r = 0; r < 4; ++r) {
                int rrow = wg * 16 + q * 4 + r;
                int col = (half * 4 + t) * 16 + mrow;
                A16[rrow * LDA + col] = cvt1_bf(fmaxf(acc2[t][r] + b1v[t], 0.f));
            }
    }
    __syncthreads();  // t1 fully written (both halves) before GEMM2 reads

    // GEMM2 (K = 128)
#pragma unroll
    for (int t = 0; t < 4; ++t) acc2[t] = (f32x4){0.f, 0.f, 0.f, 0.f};
#pragma unroll
    for (int ks = 0; ks < 4; ++ks) {
        short8 bh[4];
#pragma unroll
        for (int t = 0; t < 4; ++t) bh[t] = w2p[((size_t)(half * 4 + t) * 4 + ks) * 64 + lane];
        short8 ah = *(const short8*)&A16[arow * LDA + ks * 32 + q * 8];
#pragma unroll
        for (int t = 0; t < 4; ++t)
            acc2[t] = __builtin_amdgcn_mfma_f32_16x16x32_bf16(ah, bh[t], acc2[t], 0, 0, 0);
    }

    // ---- LayerNorm: per-wave 64-col partials, combined across halves via LDS ----
    float s4[4] = {0.f, 0.f, 0.f, 0.f}, q4[4] = {0.f, 0.f, 0.f, 0.f};
    {
        float b2v[4];
#pragma unroll
        for (int t = 0; t < 4; ++t) b2v[t] = b2[(half * 4 + t) * 16 + mrow];
#pragma unroll
        for (int t = 0; t < 4; ++t)
#pragma unroll
            for (int r = 0; r < 4; ++r) {
                float v = acc2[t][r] + b2v[t];
                acc2[t][r] = v;
                s4[r] += v;
                q4[r] += v * v;
            }
    }
#pragma unroll
    for (int m = 1; m <= 8; m <<= 1) {
#pragma unroll
        for (int r = 0; r < 4; ++r) {
            s4[r] += __shfl_xor(s4[r], m, 64);
            q4[r] += __shfl_xor(q4[r], m, 64);
        }
    }
    if (mrow == 0) {
#pragma unroll
        for (int r = 0; r < 4; ++r) {
            int rr = wg * 16 + q * 4 + r;
            sP[half * 64 + rr] = s4[r];
            qP[half * 64 + rr] = q4[r];
        }
    }
    __syncthreads();  // partials ready; also: all GEMM2 t1-reads complete before LN overwrite
    float mu[4], inv[4];
#pragma unroll
    for (int r = 0; r < 4; ++r) {
        int rr = wg * 16 + q * 4 + r;
        float s = sP[rr] + sP[64 + rr];
        float qq = qP[rr] + qP[64 + rr];
        mu[r] = s * (1.f / HDIM);
        float var = qq * (1.f / HDIM) - mu[r] * mu[r];
        inv[r] = rsqrtf(var + LN_EPS);
    }
    float gv[4], btv[4];
#pragma unroll
    for (int t = 0; t < 4; ++t) {
        gv[t] = g[(half * 4 + t) * 16 + mrow];
        btv[t] = bt[(half * 4 + t) * 16 + mrow];
    }

#pragma unroll
    for (int t = 0; t < 4; ++t)
#pragma unroll
        for (int r = 0; r < 4; ++r) {
            int rrow = wg * 16 + q * 4 + r;
            int col = (half * 4 + t) * 16 + mrow;
            float o = fmaxf((acc2[t][r] - mu[r]) * inv[r] * gv[t] + btv[t], 0.f);
            A16[rrow * LDA + col] = cvt1_bf(o);
        }
    __syncthreads();  // epilogue reads all rows

    if (!POOL) {
        // coalesced copy-out: 64 rows x 64 dwords = 4096, 8 per thread
        unsigned* xo = (unsigned*)xout;
#pragma unroll
        for (int i = 0; i < 8; ++i) {
            int idx = tid + BTH * i;
            int row = idx >> 6, w = idx & 63;
            xo[(size_t)(node0 + row) * 64 + w] = ((const unsigned*)&A16[row * LDA])[w];
        }
    } else {
        if (tid < 128) {
            int col = tid;
            float accp = 0.f;
            int cur = bidx[0];
            for (int r = 0; r < NPBLK; ++r) {
                int gi = bidx[r];
                if (gi != cur) {
                    unsafeAtomicAdd(&pool[cur * HDIM + col], accp);
                    accp = 0.f;
                    cur = gi;
                }
                accp += bf2f(A16[r * LDA + col]);
            }
            unsafeAtomicAdd(&pool[cur * HDIM + col], accp);
        } else if (tid == BTH - 1) {
            int cur = bidx[0], c = 0;
            for (int r = 0; r < NPBLK; ++r) {
                if (bidx[r] != cur) {
                    atomicAdd(&cnt[cur], c);
                    c = 0;
                    cur = bidx[r];
                }
                ++c;
            }
            atomicAdd(&cnt[cur], c);
        }
    }
}

// ---------------- din=128 fused layer: 8-thread/row gather pipeline + 8-wave tail ----------------
template <bool POOL>
__global__ __launch_bounds__(BTH, 4) void layerH_fused(
    const unsigned short* __restrict__ xin, const int* __restrict__ row_ptr,
    const int2* __restrict__ csr,
    const float* __restrict__ ew, const float* __restrict__ eb,
    const short* __restrict__ w1h, const float* __restrict__ b1,
    const short* __restrict__ w2h, const float* __restrict__ b2,
    const float* __restrict__ g, const float* __restrict__ bt,
    unsigned short* __restrict__ xout,
    const int* __restrict__ batch, float* __restrict__ pool, int* __restrict__ cnt) {
    __shared__ __align__(16) unsigned short A16[NPBLK * LDA];
    __shared__ int bidx[NPBLK];
    __shared__ __align__(16) float4 eweb4[8 * 9];  // {ew,ew,eb,eb} pairs, qt-stride 9 (conflict-free)
    __shared__ float sP[128], qP[128];             // LN partials [half][row]

    int tid = threadIdx.x;
    int node0 = blockIdx.x * NPBLK;

    if (tid < 64) {
        int qq = tid >> 3, ii = tid & 7, c = qq * 16 + ii * 2;
        eweb4[qq * 9 + ii] = make_float4(ew[c], ew[c + 1], eb[c], eb[c + 1]);
    }
    if (POOL && tid >= BTH - 64) bidx[tid - (BTH - 64)] = batch[node0 + tid - (BTH - 64)];

    // thread = (row, 16-channel eighth)
    int row = tid >> 3, qt = tid & 7, c0 = qt * 16;
    int node = node0 + row;

    // own-row load + 2-edge pipeline preamble issued before the barrier
    const uint4* xn = (const uint4*)(xin + (size_t)node * 128 + c0);
    uint4 o0 = xn[0], o1 = xn[1];
    int beg = row_ptr[node], end = row_ptr[node + 1];

    uint4 va0, va1, vb0, vb1;
    float aA = 0.f, aB = 0.f;
    if (beg < end) {
        int2 r = csr[beg];
        aA = __int_as_float(r.y);
        GLOAD(va0, va1, r.x);
    }
    if (beg + 1 < end) {
        int2 r = csr[beg + 1];
        aB = __int_as_float(r.y);
        GLOAD(vb0, vb1, r.x);
    }
    __syncthreads();  // eweb4 ready
    const float4* ep = (const float4*)eweb4 + qt * 9;

    float accs[16];
    GINIT(o0, o1);

    // software-pipelined gather: consume edge e while e+1 in flight; refill with e+2
    int e = beg;
    while (e + 3 < end) {
        GPROC(va0, va1, aA);
        {
            int2 r = csr[e + 2];
            aA = __int_as_float(r.y);
            GLOAD(va0, va1, r.x);
        }
        GPROC(vb0, vb1, aB);
        {
            int2 r = csr[e + 3];
            aB = __int_as_float(r.y);
            GLOAD(vb0, vb1, r.x);
        }
        e += 2;
    }
    if (e < end) GPROC(va0, va1, aA);
    if (e + 1 < end) GPROC(vb0, vb1, aB);
    if (e + 2 < end) {
        int2 r = csr[e + 2];
        GLOAD(va0, va1, r.x);
        GPROC(va0, va1, __int_as_float(r.y));
    }

    // packed cvt + uint2 stores
    uint2* Ar2 = (uint2*)&A16[row * LDA + c0];
#pragma unroll
    for (int k = 0; k < 4; ++k) {
        Ar2[k] = make_uint2(cvt2_bf(accs[4 * k], accs[4 * k + 1]),
                            cvt2_bf(accs[4 * k + 2], accs[4 * k + 3]));
    }
    __syncthreads();  // gather rows (8/wave) feed MFMA row-groups (16/wave) -> cross-wave

    mlp_tail8<128, POOL>(A16, bidx, sP, qP, tid, node0, w1h, b1, w2h, b2, g, bt, xout, pool, cnt);
}

// ---------------- din=5 first layer ----------------
__global__ __launch_bounds__(BTH, 4) void layer0_fused(
    const float* __restrict__ xinf, const int* __restrict__ row_ptr,
    const int2* __restrict__ csr,
    const float* __restrict__ ew, const float* __restrict__ eb,
    const short* __restrict__ w1h, const float* __restrict__ b1,
    const short* __restrict__ w2h, const float* __restrict__ b2,
    const float* __restrict__ g, const float* __restrict__ bt,
    unsigned short* __restrict__ xout) {
    __shared__ __align__(16) unsigned short A16[NPBLK * LDA];
    __shared__ float part[NPBLK][8][INDIM];
    __shared__ float sP[128], qP[128];

    int tid = threadIdx.x;
    int node0 = blockIdx.x * NPBLK;

    // 8 threads/row split the edge list; register partials
    int row = tid >> 3, qt = tid & 7;
    int node = node0 + row;
    {
        float w[INDIM], b[INDIM], acc[INDIM];
#pragma unroll
        for (int j = 0; j < INDIM; ++j) {
            w[j] = ew[j];
            b[j] = eb[j];
            acc[j] = 0.f;
        }
        int beg = row_ptr[node], end = row_ptr[node + 1];
        int2 r;
        if (beg + qt < end) r = csr[beg + qt];
        for (int e = beg + qt; e < end; e += 8) {
            int2 rn = (e + 8 < end) ? csr[e + 8] : r;
            float a = __int_as_float(r.y);
#pragma unroll
            for (int j = 0; j < INDIM; ++j)
                acc[j] += fmaxf(fmaf(a, w[j], xinf[r.x * INDIM + j] + b[j]), 0.f);
            r = rn;
        }
#pragma unroll
        for (int j = 0; j < INDIM; ++j) part[row][qt][j] = acc[j];
    }
    __syncthreads();
    if (tid < NPBLK) {
#pragma unroll
        for (int j = 0; j < INDIM; ++j) {
            float v = xinf[(node0 + tid) * INDIM + j];
#pragma unroll
            for (int k = 0; k < 8; ++k) v += part[tid][k][j];
            A16[tid * LDA + j] = cvt1_bf(v);
        }
#pragma unroll
        for (int j = INDIM; j < 32; ++j) A16[tid * LDA + j] = 0;
    }
    __syncthreads();  // rows written by tid<64 -> cross-wave

    mlp_tail8<32, false>(A16, nullptr, sP, qP, tid, node0, w1h, b1, w2h, b2, g, bt, xout,
                         nullptr, nullptr);
}

__global__ void pool_final(const float* __restrict__ pool, const int* __restrict__ cnt,
                           float* __restrict__ out) {
    int g = blockIdx.x, j = threadIdx.x;
    float add = pool[g * HDIM + j];
    float c = (float)max(cnt[g], 1);
    out[g * (2 * HDIM) + j] = add / c;
    out[g * (2 * HDIM) + HDIM + j] = add;
}

extern "C" void kernel_launch(void* const* d_in, const int* in_sizes, int n_in,
                              void* d_out, int out_size, void* d_ws, size_t ws_size,
                              hipStream_t stream) {
    const float* x_in = (const float*)d_in[0];
    const int* ei = (const int*)d_in[1];
    const float* ea = (const float*)d_in[2];
    const int* batch = (const int*)d_in[3];
    const float* P[24];
    for (int i = 0; i < 24; ++i) P[i] = (const float*)d_in[4 + i];
    // per layer l (base 8l): 0=ew 1=eb 2=w1 3=b1 4=w2 5=b2 6=g 7=bt

    unsigned short* x_a = (unsigned short*)d_ws;                 // N*128 bf16
    unsigned short* x_b = x_a + (size_t)N_NODES * HDIM;          // N*128 bf16
    float* pool = (float*)(x_b + (size_t)N_NODES * HDIM);        // G*128 (zeroed in scanA)
    int* cnt = (int*)(pool + N_GRAPHS * HDIM);                   // G    (zeroed in scanA)
    int* deg = cnt + N_GRAPHS;                                   // N    (memset)
    int* cursor = deg + N_NODES;                                 // N    (zeroed in scanC)
    int* row_ptr = cursor + N_NODES;                             // N+1
    int* bsums = row_ptr + N_NODES + 1;                          // pad 256 (keeps int2 8B-aligned)
    int2* csr = (int2*)(bsums + 256);                            // E (packed {src, val})
    short* wp = (short*)(((uintptr_t)(csr + N_EDGES) + 15) & ~(uintptr_t)15);
    float* out = (float*)d_out;

    short *w1h[3], *w2h[3];
    for (int l = 0; l < 3; ++l) {
        w1h[l] = wp + (size_t)l * 32768;
        w2h[l] = w1h[l] + 16384;
    }

    // ---- memset: deg only (pool/cnt zeroed in scanA, cursor in scanC) ----
    hipMemsetAsync(deg, 0, N_NODES * sizeof(int), stream);

    // ---- CSR build ----
    hist_kernel<<<(N_EDGES + 255) / 256, 256, 0, stream>>>(ei, deg);
    scan_phaseA<<<SCAN_BLOCKS, 256, 0, stream>>>(deg, bsums, (int*)pool);
    scan_phaseB<<<1, 256, 0, stream>>>(bsums, row_ptr);
    scan_phaseC<<<SCAN_BLOCKS, 256, 0, stream>>>(deg, bsums, row_ptr, cursor);

    // ---- fused scatter + weight packing (1563 + 336 blocks) ----
    scatter_pack<<<SCATTER_BLOCKS + 336, 256, 0, stream>>>(
        ei, ea, row_ptr, cursor, csr,
        P[2], w1h[0], P[4], w2h[0],
        P[10], w1h[1], P[12], w2h[1],
        P[18], w1h[2], P[20], w2h[2]);

    // ---- fused layers ----
    layer0_fused<<<N_NODES / NPBLK, BTH, 0, stream>>>(
        x_in, row_ptr, csr, P[0], P[1],
        w1h[0], P[3], w2h[0], P[5], P[6], P[7], x_a);
    layerH_fused<false><<<N_NODES / NPBLK, BTH, 0, stream>>>(
        x_a, row_ptr, csr, P[8], P[9],
        w1h[1], P[11], w2h[1], P[13], P[14], P[15], x_b, nullptr, nullptr, nullptr);
    layerH_fused<true><<<N_NODES / NPBLK, BTH, 0, stream>>>(
        x_b, row_ptr, csr, P[16], P[17],
        w1h[2], P[19], w2h[2], P[21], P[22], P[23], nullptr, batch, pool, cnt);

    pool_final<<<N_GRAPHS, HDIM, 0, stream>>>(pool, cnt, out);
}

// Round 6
// 389.523 us; speedup vs baseline: 1.5394x; 1.0050x over previous
//
#include <hip/hip_runtime.h>

#define N_NODES 200000
#define N_EDGES 400000
#define N_GRAPHS 64
#define HDIM 128
#define INDIM 5
#define LN_EPS 1e-5f
#define LDA 140  // 70 dwords/row: 70 mod 32 = 6 -> frag reads distributed
#define NPBLK 64 // nodes per block (8 waves x 8 rows gather; 64 rows MFMA)
#define BTH 512  // block threads: 8 threads/row -> per-thread state fits 64 VGPRs (R3/R4/R5 lesson)

typedef __attribute__((ext_vector_type(8))) short short8;
typedef __attribute__((ext_vector_type(4))) float f32x4;
typedef __attribute__((ext_vector_type(2))) float f32x2;

__device__ __forceinline__ unsigned short to_bf(float v) {
    unsigned u = __builtin_bit_cast(unsigned, v);
    return (unsigned short)((u + 0x7FFFu + ((u >> 16) & 1u)) >> 16);
}
__device__ __forceinline__ float bf_lo(unsigned w) { return __builtin_bit_cast(float, w << 16); }
__device__ __forceinline__ float bf_hi(unsigned w) { return __builtin_bit_cast(float, w & 0xFFFF0000u); }
__device__ __forceinline__ float bf2f(unsigned short h) { return __builtin_bit_cast(float, (unsigned)h << 16); }

// 1-instr RTNE f32->bf16 (same rounding as to_bf)
__device__ __forceinline__ unsigned short cvt1_bf(float v) {
    unsigned r;
    asm("v_cvt_pk_bf16_f32 %0, %1, %1" : "=v"(r) : "v"(v));
    return (unsigned short)r;
}
__device__ __forceinline__ unsigned cvt2_bf(float lo, float hi) {
    unsigned r;
    asm("v_cvt_pk_bf16_f32 %0, %1, %2" : "=v"(r) : "v"(lo), "v"(hi));
    return r;
}
__device__ __forceinline__ f32x2 vmax0(f32x2 v) {
#if __has_builtin(__builtin_elementwise_max)
    return __builtin_elementwise_max(v, (f32x2)0.f);
#else
    v.x = fmaxf(v.x, 0.f);
    v.y = fmaxf(v.y, 0.f);
    return v;
#endif
}

// ---- gather macros: 16 channels/thread (8 dwords = 2 uint4). Literal indices only,
// no staging arrays, no pointer-passed locals (R1/R3 lessons), no token pasting (R2).
#define GLOAD(p0, p1, srcrow)                                               \
    {                                                                       \
        const uint4* xs_ = (const uint4*)(xin + (size_t)(srcrow)*128 + c0); \
        p0 = xs_[0];                                                        \
        p1 = xs_[1];                                                        \
    }

// one dword wd = channel pair (2*i0, 2*i0+1): accv += relu((x + eb) + a*ew), packed f32x2
#define GP2(wd, i0)                                \
    {                                              \
        float4 wb_ = ep[i0];                       \
        f32x2 xv_;                                 \
        xv_.x = bf_lo(wd);                         \
        xv_.y = bf_hi(wd);                         \
        f32x2 ew_, eb_;                            \
        ew_.x = wb_.x;                             \
        ew_.y = wb_.y;                             \
        eb_.x = wb_.z;                             \
        eb_.y = wb_.w;                             \
        f32x2 t_ = xv_ + eb_;                      \
        t_ = av2_ * ew_ + t_;                      \
        accv[i0] += vmax0(t_);                     \
    }

#define GPROC(p0, p1, a_)                                   \
    {                                                       \
        f32x2 av2_;                                         \
        av2_.x = (a_);                                      \
        av2_.y = (a_);                                      \
        GP2(p0.x, 0) GP2(p0.y, 1) GP2(p0.z, 2) GP2(p0.w, 3) \
        GP2(p1.x, 4) GP2(p1.y, 5) GP2(p1.z, 6) GP2(p1.w, 7) \
    }

#define GI2(wd, i0)                   \
    {                                 \
        accv[i0].x = bf_lo(wd);       \
        accv[i0].y = bf_hi(wd);       \
    }

#define GINIT(p0, p1)                                       \
    {                                                       \
        GI2(p0.x, 0) GI2(p0.y, 1) GI2(p0.z, 2) GI2(p0.w, 3) \
        GI2(p1.x, 4) GI2(p1.y, 5) GI2(p1.z, 6) GI2(p1.w, 7) \
    }

// ---------------- CSR build ----------------

__global__ void hist_kernel(const int* __restrict__ ei, int* __restrict__ deg) {
    int e = blockIdx.x * blockDim.x + threadIdx.x;
    if (e < N_EDGES) atomicAdd(&deg[ei[N_EDGES + e]], 1);
}

#define SCAN_CHUNK 1024
#define SCAN_BLOCKS ((N_NODES + SCAN_CHUNK - 1) / SCAN_CHUNK)  // 196

__global__ __launch_bounds__(256) void scan_phaseA(const int* __restrict__ deg, int* __restrict__ bsums,
                                                   int* __restrict__ poolz) {
    if (blockIdx.x == 0) {
        for (int i = threadIdx.x; i < N_GRAPHS * HDIM + N_GRAPHS; i += 256) poolz[i] = 0;
    }
    __shared__ int red[256];
    int t = threadIdx.x;
    int base = blockIdx.x * SCAN_CHUNK + t * 4;
    int s = 0;
#pragma unroll
    for (int k = 0; k < 4; ++k) {
        int i = base + k;
        s += (i < N_NODES) ? deg[i] : 0;
    }
    red[t] = s;
    __syncthreads();
    for (int off = 128; off; off >>= 1) {
        if (t < off) red[t] += red[t + off];
        __syncthreads();
    }
    if (t == 0) bsums[blockIdx.x] = red[0];
}

__global__ __launch_bounds__(256) void scan_phaseB(int* __restrict__ bsums, int* __restrict__ row_ptr) {
    __shared__ int s[256];
    int t = threadIdx.x;
    int v = (t < SCAN_BLOCKS) ? bsums[t] : 0;
    s[t] = v;
    __syncthreads();
    for (int off = 1; off < 256; off <<= 1) {
        int add = (t >= off) ? s[t - off] : 0;
        __syncthreads();
        s[t] += add;
        __syncthreads();
    }
    if (t < SCAN_BLOCKS) bsums[t] = s[t] - v;  // exclusive
    if (t == SCAN_BLOCKS - 1) row_ptr[N_NODES] = s[t];
}

__global__ __launch_bounds__(256) void scan_phaseC(const int* __restrict__ deg,
                                                   const int* __restrict__ bsums,
                                                   int* __restrict__ row_ptr,
                                                   int* __restrict__ cursor) {
    __shared__ int ts[256];
    int t = threadIdx.x;
    int base = blockIdx.x * SCAN_CHUNK + t * 4;
    int v[4];
    int s = 0;
#pragma unroll
    for (int k = 0; k < 4; ++k) {
        int i = base + k;
        v[k] = (i < N_NODES) ? deg[i] : 0;
        s += v[k];
    }
    ts[t] = s;
    __syncthreads();
    for (int off = 1; off < 256; off <<= 1) {
        int add = (t >= off) ? ts[t - off] : 0;
        __syncthreads();
        ts[t] += add;
        __syncthreads();
    }
    int run = bsums[blockIdx.x] + ts[t] - s;
#pragma unroll
    for (int k = 0; k < 4; ++k) {
        int i = base + k;
        if (i < N_NODES) { row_ptr[i] = run; cursor[i] = 0; }
        run += v[k];
    }
}

// ---------------- Fused scatter (CSR fill) + weight packing ----------------
#define SCATTER_BLOCKS ((N_EDGES + 255) / 256)  // 1563

__global__ void scatter_pack(const int* __restrict__ ei, const float* __restrict__ ea,
                             const int* __restrict__ row_ptr, int* __restrict__ cursor,
                             int2* __restrict__ csr,
                             const float* __restrict__ s0, short* __restrict__ d0,
                             const float* __restrict__ s1, short* __restrict__ d1,
                             const float* __restrict__ s2, short* __restrict__ d2,
                             const float* __restrict__ s3, short* __restrict__ d3,
                             const float* __restrict__ s4, short* __restrict__ d4,
                             const float* __restrict__ s5, short* __restrict__ d5) {
    int b = blockIdx.x;
    if (b < SCATTER_BLOCKS) {
        int e = b * 256 + threadIdx.x;
        if (e >= N_EDGES) return;
        int d = ei[N_EDGES + e];
        int pos = atomicAdd(&cursor[d], 1);
        csr[row_ptr[d] + pos] = make_int2(ei[e], __float_as_int(ea[e]));
        return;
    }
    b -= SCATTER_BLOCKS;
    const float* W;
    short* D;
    int din, KP, b0;
    if (b < 16)       { W = s0; D = d0; din = 5;   KP = 32;  b0 = 0; }
    else if (b < 80)  { W = s1; D = d1; din = 128; KP = 128; b0 = 16; }
    else if (b < 144) { W = s2; D = d2; din = 128; KP = 128; b0 = 80; }
    else if (b < 208) { W = s3; D = d3; din = 128; KP = 128; b0 = 144; }
    else if (b < 272) { W = s4; D = d4; din = 128; KP = 128; b0 = 208; }
    else              { W = s5; D = d5; din = 128; KP = 128; b0 = 272; }
    int idx = (b - b0) * 256 + threadIdx.x;
    if (idx >= KP * 128) return;
    int j = idx & 7;
    int lane = (idx >> 3) & 63;
    int rest = idx >> 9;
    int KS = KP >> 5;
    int kstep = rest % KS;
    int tile = rest / KS;
    int k = kstep * 32 + ((lane >> 4) * 8) + j;
    int n = tile * 16 + (lane & 15);
    float v = (k < din) ? W[k * 128 + n] : 0.f;
    D[idx] = (short)to_bf(v);
}

// ---------------- shared 8-wave MFMA MLP + reg-LN + ReLU (+pool) tail ----------------
// wave wv: row-group (wv&3) = rows [16*(wv&3), +16), column-half (wv>>2) = tiles
// [4*half, 4*half+4). LN row-sums combined across halves via sP/qP LDS partials.
template <int KP1, bool POOL>
__device__ __forceinline__ void mlp_tail8(
    unsigned short* A16, const int* bidx, float* sP, float* qP, int tid, int node0,
    const short* __restrict__ w1h, const float* __restrict__ b1,
    const short* __restrict__ w2h, const float* __restrict__ b2,
    const float* __restrict__ g, const float* __restrict__ bt,
    unsigned short* __restrict__ xout, float* __restrict__ pool, int* __restrict__ cnt) {
    int wv = tid >> 6, lane = tid & 63;
    int wg = wv & 3, half = wv >> 2;
    int mrow = lane & 15, q = lane >> 4;
    int arow = wg * 16 + mrow;

    const short8* w1p = (const short8*)w1h;
    const short8* w2p = (const short8*)w2h;

    f32x4 acc2[4];
#pragma unroll
    for (int t = 0; t < 4; ++t) acc2[t] = (f32x4){0.f, 0.f, 0.f, 0.f};
    constexpr int KS1 = KP1 / 32;
#pragma unroll
    for (int ks = 0; ks < KS1; ++ks) {
        short8 bh[4];
#pragma unroll
        for (int t = 0; t < 4; ++t) bh[t] = w1p[((size_t)(half * 4 + t) * KS1 + ks) * 64 + lane];
        short8 ah = *(const short8*)&A16[arow * LDA + ks * 32 + q * 8];
#pragma unroll
        for (int t = 0; t < 4; ++t)
            acc2[t] = __builtin_amdgcn_mfma_f32_16x16x32_bf16(ah, bh[t], acc2[t], 0, 0, 0);
    }
    __syncthreads();  // all waves done reading layer-A before t1 overwrites rows
    // t1 = relu(acc + b1) -> bf16 A (this wave's column half of its row group)
    {
        float b1v[4];
#pragma unroll
        for (int t = 0; t < 4; ++t) b1v[t] = b1[(half * 4 + t) * 16 + mrow];
#pragma unroll
        for (int t = 0; t < 4; ++t)
#pragma unroll
            for (int r = 0; r < 4; ++r) {
                int rrow = wg * 16 + q * 4 + r;
                int col = (half * 4 + t) * 16 + mrow;
                A16[rrow * LDA + col] = cvt1_bf(fmaxf(acc2[t][r] + b1v[t], 0.f));
            }
    }
    __syncthreads();  // t1 fully written (both halves) before GEMM2 reads

    // GEMM2 (K = 128)
#pragma unroll
    for (int t = 0; t < 4; ++t) acc2[t] = (f32x4){0.f, 0.f, 0.f, 0.f};
#pragma unroll
    for (int ks = 0; ks < 4; ++ks) {
        short8 bh[4];
#pragma unroll
        for (int t = 0; t < 4; ++t) bh[t] = w2p[((size_t)(half * 4 + t) * 4 + ks) * 64 + lane];
        short8 ah = *(const short8*)&A16[arow * LDA + ks * 32 + q * 8];
#pragma unroll
        for (int t = 0; t < 4; ++t)
            acc2[t] = __builtin_amdgcn_mfma_f32_16x16x32_bf16(ah, bh[t], acc2[t], 0, 0, 0);
    }

    // ---- LayerNorm: per-wave 64-col partials, combined across halves via LDS ----
    float s4[4] = {0.f, 0.f, 0.f, 0.f}, q4[4] = {0.f, 0.f, 0.f, 0.f};
    {
        float b2v[4];
#pragma unroll
        for (int t = 0; t < 4; ++t) b2v[t] = b2[(half * 4 + t) * 16 + mrow];
#pragma unroll
        for (int t = 0; t < 4; ++t)
#pragma unroll
            for (int r = 0; r < 4; ++r) {
                float v = acc2[t][r] + b2v[t];
                acc2[t][r] = v;
                s4[r] += v;
                q4[r] += v * v;
            }
    }
#pragma unroll
    for (int m = 1; m <= 8; m <<= 1) {
#pragma unroll
        for (int r = 0; r < 4; ++r) {
            s4[r] += __shfl_xor(s4[r], m, 64);
            q4[r] += __shfl_xor(q4[r], m, 64);
        }
    }
    if (mrow == 0) {
#pragma unroll
        for (int r = 0; r < 4; ++r) {
            int rr = wg * 16 + q * 4 + r;
            sP[half * 64 + rr] = s4[r];
            qP[half * 64 + rr] = q4[r];
        }
    }
    __syncthreads();  // partials ready; also: all GEMM2 t1-reads complete before LN overwrite
    float mu[4], inv[4];
#pragma unroll
    for (int r = 0; r < 4; ++r) {
        int rr = wg * 16 + q * 4 + r;
        float s = sP[rr] + sP[64 + rr];
        float qq = qP[rr] + qP[64 + rr];
        mu[r] = s * (1.f / HDIM);
        float var = qq * (1.f / HDIM) - mu[r] * mu[r];
        inv[r] = rsqrtf(var + LN_EPS);
    }
    float gv[4], btv[4];
#pragma unroll
    for (int t = 0; t < 4; ++t) {
        gv[t] = g[(half * 4 + t) * 16 + mrow];
        btv[t] = bt[(half * 4 + t) * 16 + mrow];
    }

#pragma unroll
    for (int t = 0; t < 4; ++t)
#pragma unroll
        for (int r = 0; r < 4; ++r) {
            int rrow = wg * 16 + q * 4 + r;
            int col = (half * 4 + t) * 16 + mrow;
            float o = fmaxf((acc2[t][r] - mu[r]) * inv[r] * gv[t] + btv[t], 0.f);
            A16[rrow * LDA + col] = cvt1_bf(o);
        }
    __syncthreads();  // epilogue reads all rows

    if (!POOL) {
        // coalesced copy-out: 64 rows x 64 dwords = 4096, 8 per thread
        unsigned* xo = (unsigned*)xout;
#pragma unroll
        for (int i = 0; i < 8; ++i) {
            int idx = tid + BTH * i;
            int row = idx >> 6, w = idx & 63;
            xo[(size_t)(node0 + row) * 64 + w] = ((const unsigned*)&A16[row * LDA])[w];
        }
    } else {
        if (tid < 128) {
            int col = tid;
            float accp = 0.f;
            int cur = bidx[0];
            for (int r = 0; r < NPBLK; ++r) {
                int gi = bidx[r];
                if (gi != cur) {
                    unsafeAtomicAdd(&pool[cur * HDIM + col], accp);
                    accp = 0.f;
                    cur = gi;
                }
                accp += bf2f(A16[r * LDA + col]);
            }
            unsafeAtomicAdd(&pool[cur * HDIM + col], accp);
        } else if (tid == BTH - 1) {
            int cur = bidx[0], c = 0;
            for (int r = 0; r < NPBLK; ++r) {
                if (bidx[r] != cur) {
                    atomicAdd(&cnt[cur], c);
                    c = 0;
                    cur = bidx[r];
                }
                ++c;
            }
            atomicAdd(&cnt[cur], c);
        }
    }
}

// ---------------- din=128 fused layer: distance-2 csr prefetch + 2-deep x pipeline ----------------
// R5 lesson: csr record consumed at its issue point forces a near-vmcnt(0) drain killing the
// x-row pipeline. Fix: records resident 2 iterations before their GLOAD; in-loop csr loads are
// UNCONDITIONAL with clamped address (a guarded load puts a draining waitcnt at the branch merge).
template <bool POOL>
__global__ __launch_bounds__(BTH, 4) void layerH_fused(
    const unsigned short* __restrict__ xin, const int* __restrict__ row_ptr,
    const int2* __restrict__ csr,
    const float* __restrict__ ew, const float* __restrict__ eb,
    const short* __restrict__ w1h, const float* __restrict__ b1,
    const short* __restrict__ w2h, const float* __restrict__ b2,
    const float* __restrict__ g, const float* __restrict__ bt,
    unsigned short* __restrict__ xout,
    const int* __restrict__ batch, float* __restrict__ pool, int* __restrict__ cnt) {
    __shared__ __align__(16) unsigned short A16[NPBLK * LDA];
    __shared__ int bidx[NPBLK];
    __shared__ __align__(16) float4 eweb4[8 * 9];  // {ew,ew,eb,eb} pairs, qt-stride 9 (conflict-free)
    __shared__ float sP[128], qP[128];             // LN partials [half][row]

    int tid = threadIdx.x;
    int node0 = blockIdx.x * NPBLK;

    if (tid < 64) {
        int qq = tid >> 3, ii = tid & 7, c = qq * 16 + ii * 2;
        eweb4[qq * 9 + ii] = make_float4(ew[c], ew[c + 1], eb[c], eb[c + 1]);
    }
    if (POOL && tid >= BTH - 64) bidx[tid - (BTH - 64)] = batch[node0 + tid - (BTH - 64)];

    // thread = (row, 16-channel eighth)
    int row = tid >> 3, qt = tid & 7, c0 = qt * 16;
    int node = node0 + row;

    // own-row load + pipeline preamble issued before the barrier (in flight across it)
    const uint4* xn = (const uint4*)(xin + (size_t)node * 128 + c0);
    uint4 o0 = xn[0], o1 = xn[1];
    int beg = row_ptr[node], end = row_ptr[node + 1];

    uint4 va0, va1, vb0, vb1;
    float aA = 0.f, aB = 0.f;
    int2 rC = make_int2(0, 0), rD = rC, rE = rC, rF = rC;
    if (beg < end) {
        int2 r = csr[beg];
        aA = __int_as_float(r.y);
        GLOAD(va0, va1, r.x);
    }
    if (beg + 1 < end) {
        int2 r = csr[beg + 1];
        aB = __int_as_float(r.y);
        GLOAD(vb0, vb1, r.x);
    }
    if (beg + 2 < end) rC = csr[beg + 2];
    if (beg + 3 < end) rD = csr[beg + 3];
    if (beg + 4 < end) rE = csr[beg + 4];
    if (beg + 5 < end) rF = csr[beg + 5];
    __syncthreads();  // eweb4 ready
    const float4* ep = (const float4*)eweb4 + qt * 9;

    f32x2 accv[8];
    GINIT(o0, o1);

    // steady state: xa/xb in flight (edges e,e+1), rC/rD resident (e+2,e+3), rE/rF in flight (e+4,e+5)
    int e = beg;
    while (e + 3 < end) {
        GPROC(va0, va1, aA);       // partial wait: only xa drains
        GLOAD(va0, va1, rC.x);     // rC resident since 2 iterations ago -> no wait
        aA = __int_as_float(rC.y);
        GPROC(vb0, vb1, aB);
        GLOAD(vb0, vb1, rD.x);
        aB = __int_as_float(rD.y);
        rC = rE;                   // rE is 1 iteration old -> cheap partial wait
        rD = rF;
        int i6 = min(e + 6, end - 1);  // end >= e+4 > 0 inside loop -> clamp is safe
        int i7 = min(e + 7, end - 1);
        rE = csr[i6];              // unconditional: no branch-merge waitcnt
        rF = csr[i7];
        e += 2;
    }
    // drain: at most 3 edges remain (e, e+1, e+2)
    if (e < end) GPROC(va0, va1, aA);
    if (e + 1 < end) GPROC(vb0, vb1, aB);
    if (e + 2 < end) {
        GLOAD(va0, va1, rC.x);
        GPROC(va0, va1, __int_as_float(rC.y));
    }

    // packed cvt + uint2 stores
    uint2* Ar2 = (uint2*)&A16[row * LDA + c0];
#pragma unroll
    for (int k = 0; k < 4; ++k) {
        Ar2[k] = make_uint2(cvt2_bf(accv[2 * k].x, accv[2 * k].y),
                            cvt2_bf(accv[2 * k + 1].x, accv[2 * k + 1].y));
    }
    __syncthreads();  // gather rows (8/wave) feed MFMA row-groups (16/wave) -> cross-wave

    mlp_tail8<128, POOL>(A16, bidx, sP, qP, tid, node0, w1h, b1, w2h, b2, g, bt, xout, pool, cnt);
}

// ---------------- din=5 first layer ----------------
__global__ __launch_bounds__(BTH, 4) void layer0_fused(
    const float* __restrict__ xinf, const int* __restrict__ row_ptr,
    const int2* __restrict__ csr,
    const float* __restrict__ ew, const float* __restrict__ eb,
    const short* __restrict__ w1h, const float* __restrict__ b1,
    const short* __restrict__ w2h, const float* __restrict__ b2,
    const float* __restrict__ g, const float* __restrict__ bt,
    unsigned short* __restrict__ xout) {
    __shared__ __align__(16) unsigned short A16[NPBLK * LDA];
    __shared__ float part[NPBLK][8][INDIM];
    __shared__ float sP[128], qP[128];

    int tid = threadIdx.x;
    int node0 = blockIdx.x * NPBLK;

    // 8 threads/row split the edge list; register partials
    int row = tid >> 3, qt = tid & 7;
    int node = node0 + row;
    {
        float w[INDIM], b[INDIM], acc[INDIM];
#pragma unroll
        for (int j = 0; j < INDIM; ++j) {
            w[j] = ew[j];
            b[j] = eb[j];
            acc[j] = 0.f;
        }
        int beg = row_ptr[node], end = row_ptr[node + 1];
        int2 r;
        if (beg + qt < end) r = csr[beg + qt];
        for (int e = beg + qt; e < end; e += 8) {
            int2 rn = (e + 8 < end) ? csr[e + 8] : r;
            float a = __int_as_float(r.y);
#pragma unroll
            for (int j = 0; j < INDIM; ++j)
                acc[j] += fmaxf(fmaf(a, w[j], xinf[r.x * INDIM + j] + b[j]), 0.f);
            r = rn;
        }
#pragma unroll
        for (int j = 0; j < INDIM; ++j) part[row][qt][j] = acc[j];
    }
    __syncthreads();
    if (tid < NPBLK) {
#pragma unroll
        for (int j = 0; j < INDIM; ++j) {
            float v = xinf[(node0 + tid) * INDIM + j];
#pragma unroll
            for (int k = 0; k < 8; ++k) v += part[tid][k][j];
            A16[tid * LDA + j] = cvt1_bf(v);
        }
#pragma unroll
        for (int j = INDIM; j < 32; ++j) A16[tid * LDA + j] = 0;
    }
    __syncthreads();  // rows written by tid<64 -> cross-wave

    mlp_tail8<32, false>(A16, nullptr, sP, qP, tid, node0, w1h, b1, w2h, b2, g, bt, xout,
                         nullptr, nullptr);
}

__global__ void pool_final(const float* __restrict__ pool, const int* __restrict__ cnt,
                           float* __restrict__ out) {
    int g = blockIdx.x, j = threadIdx.x;
    float add = pool[g * HDIM + j];
    float c = (float)max(cnt[g], 1);
    out[g * (2 * HDIM) + j] = add / c;
    out[g * (2 * HDIM) + HDIM + j] = add;
}

extern "C" void kernel_launch(void* const* d_in, const int* in_sizes, int n_in,
                              void* d_out, int out_size, void* d_ws, size_t ws_size,
                              hipStream_t stream) {
    const float* x_in = (const float*)d_in[0];
    const int* ei = (const int*)d_in[1];
    const float* ea = (const float*)d_in[2];
    const int* batch = (const int*)d_in[3];
    const float* P[24];
    for (int i = 0; i < 24; ++i) P[i] = (const float*)d_in[4 + i];
    // per layer l (base 8l): 0=ew 1=eb 2=w1 3=b1 4=w2 5=b2 6=g 7=bt

    unsigned short* x_a = (unsigned short*)d_ws;                 // N*128 bf16
    unsigned short* x_b = x_a + (size_t)N_NODES * HDIM;          // N*128 bf16
    float* pool = (float*)(x_b + (size_t)N_NODES * HDIM);        // G*128 (zeroed in scanA)
    int* cnt = (int*)(pool + N_GRAPHS * HDIM);                   // G    (zeroed in scanA)
    int* deg = cnt + N_GRAPHS;                                   // N    (memset)
    int* cursor = deg + N_NODES;                                 // N    (zeroed in scanC)
    int* row_ptr = cursor + N_NODES;                             // N+1
    int* bsums = row_ptr + N_NODES + 1;                          // pad 256 (keeps int2 8B-aligned)
    int2* csr = (int2*)(bsums + 256);                            // E (packed {src, val})
    short* wp = (short*)(((uintptr_t)(csr + N_EDGES) + 15) & ~(uintptr_t)15);
    float* out = (float*)d_out;

    short *w1h[3], *w2h[3];
    for (int l = 0; l < 3; ++l) {
        w1h[l] = wp + (size_t)l * 32768;
        w2h[l] = w1h[l] + 16384;
    }

    // ---- memset: deg only (pool/cnt zeroed in scanA, cursor in scanC) ----
    hipMemsetAsync(deg, 0, N_NODES * sizeof(int), stream);

    // ---- CSR build ----
    hist_kernel<<<(N_EDGES + 255) / 256, 256, 0, stream>>>(ei, deg);
    scan_phaseA<<<SCAN_BLOCKS, 256, 0, stream>>>(deg, bsums, (int*)pool);
    scan_phaseB<<<1, 256, 0, stream>>>(bsums, row_ptr);
    scan_phaseC<<<SCAN_BLOCKS, 256, 0, stream>>>(deg, bsums, row_ptr, cursor);

    // ---- fused scatter + weight packing (1563 + 336 blocks) ----
    scatter_pack<<<SCATTER_BLOCKS + 336, 256, 0, stream>>>(
        ei, ea, row_ptr, cursor, csr,
        P[2], w1h[0], P[4], w2h[0],
        P[10], w1h[1], P[12], w2h[1],
        P[18], w1h[2], P[20], w2h[2]);

    // ---- fused layers ----
    layer0_fused<<<N_NODES / NPBLK, BTH, 0, stream>>>(
        x_in, row_ptr, csr, P[0], P[1],
        w1h[0], P[3], w2h[0], P[5], P[6], P[7], x_a);
    layerH_fused<false><<<N_NODES / NPBLK, BTH, 0, stream>>>(
        x_a, row_ptr, csr, P[8], P[9],
        w1h[1], P[11], w2h[1], P[13], P[14], P[15], x_b, nullptr, nullptr, nullptr);
    layerH_fused<true><<<N_NODES / NPBLK, BTH, 0, stream>>>(
        x_b, row_ptr, csr, P[16], P[17],
        w1h[2], P[19], w2h[2], P[21], P[22], P[23], nullptr, batch, pool, cnt);

    pool_final<<<N_GRAPHS, HDIM, 0, stream>>>(pool, cnt, out);
}

// Round 7
// 381.788 us; speedup vs baseline: 1.5706x; 1.0203x over previous
//
#include <hip/hip_runtime.h>

#define N_NODES 200000
#define N_EDGES 400000
#define N_GRAPHS 64
#define HDIM 128
#define INDIM 5
#define LN_EPS 1e-5f
#define LDA 140   // 70 dwords/row: 70 mod 32 = 6 -> frag reads distributed
#define NPBLK 64  // rows per MLP block (4 waves x 16 wave-local rows -- R0-proven tail)
#define GROWS 32  // rows per gather block (8 thr/row x 256 thr)

typedef __attribute__((ext_vector_type(8))) short short8;
typedef __attribute__((ext_vector_type(4))) float f32x4;
typedef __attribute__((ext_vector_type(2))) float f32x2;

__device__ __forceinline__ unsigned short to_bf(float v) {
    unsigned u = __builtin_bit_cast(unsigned, v);
    return (unsigned short)((u + 0x7FFFu + ((u >> 16) & 1u)) >> 16);
}
__device__ __forceinline__ float bf_lo(unsigned w) { return __builtin_bit_cast(float, w << 16); }
__device__ __forceinline__ float bf_hi(unsigned w) { return __builtin_bit_cast(float, w & 0xFFFF0000u); }
__device__ __forceinline__ float bf2f(unsigned short h) { return __builtin_bit_cast(float, (unsigned)h << 16); }

// 1-instr RTNE f32->bf16 (same rounding as to_bf)
__device__ __forceinline__ unsigned short cvt1_bf(float v) {
    unsigned r;
    asm("v_cvt_pk_bf16_f32 %0, %1, %1" : "=v"(r) : "v"(v));
    return (unsigned short)r;
}
__device__ __forceinline__ unsigned cvt2_bf(float lo, float hi) {
    unsigned r;
    asm("v_cvt_pk_bf16_f32 %0, %1, %2" : "=v"(r) : "v"(lo), "v"(hi));
    return r;
}
__device__ __forceinline__ f32x2 vmax0(f32x2 v) {
#if __has_builtin(__builtin_elementwise_max)
    return __builtin_elementwise_max(v, (f32x2)0.f);
#else
    v.x = fmaxf(v.x, 0.f);
    v.y = fmaxf(v.y, 0.f);
    return v;
#endif
}

// ---- gather macros (R6-proven clean codegen): 16 ch/thread, literal indices only,
// no staging arrays, no pointer-passed locals, no token pasting.
#define GLOAD(p0, p1, srcrow)                                               \
    {                                                                       \
        const uint4* xs_ = (const uint4*)(xin + (size_t)(srcrow)*128 + c0); \
        p0 = xs_[0];                                                        \
        p1 = xs_[1];                                                        \
    }

#define GP2(wd, i0)                  \
    {                                \
        float4 wb_ = ep[i0];         \
        f32x2 xv_;                   \
        xv_.x = bf_lo(wd);           \
        xv_.y = bf_hi(wd);           \
        f32x2 ew_, eb_;              \
        ew_.x = wb_.x;               \
        ew_.y = wb_.y;               \
        eb_.x = wb_.z;               \
        eb_.y = wb_.w;               \
        f32x2 t_ = xv_ + eb_;        \
        t_ = av2_ * ew_ + t_;        \
        accv[i0] += vmax0(t_);       \
    }

#define GPROC(p0, p1, a_)                                   \
    {                                                       \
        f32x2 av2_;                                         \
        av2_.x = (a_);                                      \
        av2_.y = (a_);                                      \
        GP2(p0.x, 0) GP2(p0.y, 1) GP2(p0.z, 2) GP2(p0.w, 3) \
        GP2(p1.x, 4) GP2(p1.y, 5) GP2(p1.z, 6) GP2(p1.w, 7) \
    }

#define GI2(wd, i0)                   \
    {                                 \
        accv[i0].x = bf_lo(wd);       \
        accv[i0].y = bf_hi(wd);       \
    }

#define GINIT(p0, p1)                                       \
    {                                                       \
        GI2(p0.x, 0) GI2(p0.y, 1) GI2(p0.z, 2) GI2(p0.w, 3) \
        GI2(p1.x, 4) GI2(p1.y, 5) GI2(p1.z, 6) GI2(p1.w, 7) \
    }

// ---------------- CSR build ----------------

__global__ void hist_kernel(const int* __restrict__ ei, int* __restrict__ deg) {
    int e = blockIdx.x * blockDim.x + threadIdx.x;
    if (e < N_EDGES) atomicAdd(&deg[ei[N_EDGES + e]], 1);
}

#define SCAN_CHUNK 1024
#define SCAN_BLOCKS ((N_NODES + SCAN_CHUNK - 1) / SCAN_CHUNK)  // 196

__global__ __launch_bounds__(256) void scan_phaseA(const int* __restrict__ deg, int* __restrict__ bsums,
                                                   int* __restrict__ poolz) {
    if (blockIdx.x == 0) {
        for (int i = threadIdx.x; i < N_GRAPHS * HDIM + N_GRAPHS; i += 256) poolz[i] = 0;
    }
    __shared__ int red[256];
    int t = threadIdx.x;
    int base = blockIdx.x * SCAN_CHUNK + t * 4;
    int s = 0;
#pragma unroll
    for (int k = 0; k < 4; ++k) {
        int i = base + k;
        s += (i < N_NODES) ? deg[i] : 0;
    }
    red[t] = s;
    __syncthreads();
    for (int off = 128; off; off >>= 1) {
        if (t < off) red[t] += red[t + off];
        __syncthreads();
    }
    if (t == 0) bsums[blockIdx.x] = red[0];
}

__global__ __launch_bounds__(256) void scan_phaseB(int* __restrict__ bsums, int* __restrict__ row_ptr) {
    __shared__ int s[256];
    int t = threadIdx.x;
    int v = (t < SCAN_BLOCKS) ? bsums[t] : 0;
    s[t] = v;
    __syncthreads();
    for (int off = 1; off < 256; off <<= 1) {
        int add = (t >= off) ? s[t - off] : 0;
        __syncthreads();
        s[t] += add;
        __syncthreads();
    }
    if (t < SCAN_BLOCKS) bsums[t] = s[t] - v;  // exclusive
    if (t == SCAN_BLOCKS - 1) row_ptr[N_NODES] = s[t];
}

__global__ __launch_bounds__(256) void scan_phaseC(const int* __restrict__ deg,
                                                   const int* __restrict__ bsums,
                                                   int* __restrict__ row_ptr,
                                                   int* __restrict__ cursor) {
    __shared__ int ts[256];
    int t = threadIdx.x;
    int base = blockIdx.x * SCAN_CHUNK + t * 4;
    int v[4];
    int s = 0;
#pragma unroll
    for (int k = 0; k < 4; ++k) {
        int i = base + k;
        v[k] = (i < N_NODES) ? deg[i] : 0;
        s += v[k];
    }
    ts[t] = s;
    __syncthreads();
    for (int off = 1; off < 256; off <<= 1) {
        int add = (t >= off) ? ts[t - off] : 0;
        __syncthreads();
        ts[t] += add;
        __syncthreads();
    }
    int run = bsums[blockIdx.x] + ts[t] - s;
#pragma unroll
    for (int k = 0; k < 4; ++k) {
        int i = base + k;
        if (i < N_NODES) { row_ptr[i] = run; cursor[i] = 0; }
        run += v[k];
    }
}

// ---------------- Fused scatter (CSR fill) + weight packing ----------------
#define SCATTER_BLOCKS ((N_EDGES + 255) / 256)  // 1563

__global__ void scatter_pack(const int* __restrict__ ei, const float* __restrict__ ea,
                             const int* __restrict__ row_ptr, int* __restrict__ cursor,
                             int2* __restrict__ csr,
                             const float* __restrict__ s0, short* __restrict__ d0,
                             const float* __restrict__ s1, short* __restrict__ d1,
                             const float* __restrict__ s2, short* __restrict__ d2,
                             const float* __restrict__ s3, short* __restrict__ d3,
                             const float* __restrict__ s4, short* __restrict__ d4,
                             const float* __restrict__ s5, short* __restrict__ d5) {
    int b = blockIdx.x;
    if (b < SCATTER_BLOCKS) {
        int e = b * 256 + threadIdx.x;
        if (e >= N_EDGES) return;
        int d = ei[N_EDGES + e];
        int pos = atomicAdd(&cursor[d], 1);
        csr[row_ptr[d] + pos] = make_int2(ei[e], __float_as_int(ea[e]));
        return;
    }
    b -= SCATTER_BLOCKS;
    const float* W;
    short* D;
    int din, KP, b0;
    if (b < 16)       { W = s0; D = d0; din = 5;   KP = 32;  b0 = 0; }
    else if (b < 80)  { W = s1; D = d1; din = 128; KP = 128; b0 = 16; }
    else if (b < 144) { W = s2; D = d2; din = 128; KP = 128; b0 = 80; }
    else if (b < 208) { W = s3; D = d3; din = 128; KP = 128; b0 = 144; }
    else if (b < 272) { W = s4; D = d4; din = 128; KP = 128; b0 = 208; }
    else              { W = s5; D = d5; din = 128; KP = 128; b0 = 272; }
    int idx = (b - b0) * 256 + threadIdx.x;
    if (idx >= KP * 128) return;
    int j = idx & 7;
    int lane = (idx >> 3) & 63;
    int rest = idx >> 9;
    int KS = KP >> 5;
    int kstep = rest % KS;
    int tile = rest / KS;
    int k = kstep * 32 + ((lane >> 4) * 8) + j;
    int n = tile * 16 + (lane & 15);
    float v = (k < din) ? W[k * 128 + n] : 0.f;
    D[idx] = (short)to_bf(v);
}

// ---------------- gatherH: din=128 gather-only (latency machine) ----------------
// 256 thr = 32 rows x 8 thr/row; no MFMA tail, no barriers after eweb; LDS ~1.2KB ->
// residency wave-capped (32 waves/CU). Writes h = x + sum(relu(x_j + a*ew + eb)) as bf16.
__global__ __launch_bounds__(256, 4) void gatherH(
    const unsigned short* __restrict__ xin, const int* __restrict__ row_ptr,
    const int2* __restrict__ csr,
    const float* __restrict__ ew, const float* __restrict__ eb,
    unsigned short* __restrict__ hout) {
    __shared__ __align__(16) float4 eweb4[8 * 9];  // {ew,ew,eb,eb} pairs, qt-stride 9

    int tid = threadIdx.x;
    if (tid < 64) {
        int qq = tid >> 3, ii = tid & 7, c = qq * 16 + ii * 2;
        eweb4[qq * 9 + ii] = make_float4(ew[c], ew[c + 1], eb[c], eb[c + 1]);
    }

    int row = tid >> 3, qt = tid & 7, c0 = qt * 16;
    int node = blockIdx.x * GROWS + row;

    const uint4* xn = (const uint4*)(xin + (size_t)node * 128 + c0);
    uint4 o0 = xn[0], o1 = xn[1];
    int beg = row_ptr[node], end = row_ptr[node + 1];

    // 2-deep x pipeline + distance-2 csr prefetch (R6-proven codegen)
    uint4 va0, va1, vb0, vb1;
    float aA = 0.f, aB = 0.f;
    int2 rC = make_int2(0, 0), rD = rC, rE = rC, rF = rC;
    if (beg < end) {
        int2 r = csr[beg];
        aA = __int_as_float(r.y);
        GLOAD(va0, va1, r.x);
    }
    if (beg + 1 < end) {
        int2 r = csr[beg + 1];
        aB = __int_as_float(r.y);
        GLOAD(vb0, vb1, r.x);
    }
    if (beg + 2 < end) rC = csr[beg + 2];
    if (beg + 3 < end) rD = csr[beg + 3];
    if (beg + 4 < end) rE = csr[beg + 4];
    if (beg + 5 < end) rF = csr[beg + 5];
    __syncthreads();  // eweb4 ready
    const float4* ep = (const float4*)eweb4 + qt * 9;

    f32x2 accv[8];
    GINIT(o0, o1);

    int e = beg;
    while (e + 3 < end) {
        GPROC(va0, va1, aA);
        GLOAD(va0, va1, rC.x);
        aA = __int_as_float(rC.y);
        GPROC(vb0, vb1, aB);
        GLOAD(vb0, vb1, rD.x);
        aB = __int_as_float(rD.y);
        rC = rE;
        rD = rF;
        int i6 = min(e + 6, end - 1);
        int i7 = min(e + 7, end - 1);
        rE = csr[i6];
        rF = csr[i7];
        e += 2;
    }
    if (e < end) GPROC(va0, va1, aA);
    if (e + 1 < end) GPROC(vb0, vb1, aB);
    if (e + 2 < end) {
        GLOAD(va0, va1, rC.x);
        GPROC(va0, va1, __int_as_float(rC.y));
    }

    // coalesced-ish bf16 store of this thread's 16-channel slice
    uint2* ho = (uint2*)(hout + (size_t)node * 128 + c0);
#pragma unroll
    for (int k = 0; k < 4; ++k) {
        ho[k] = make_uint2(cvt2_bf(accv[2 * k].x, accv[2 * k].y),
                           cvt2_bf(accv[2 * k + 1].x, accv[2 * k + 1].y));
    }
}

// ---------------- gather0: din=5 gather-only, 1 thr/row ----------------
// Writes h0 rows padded to 32 bf16 ch (5 real + 27 zeros; weight rows k>=5 are zero-packed,
// but stale workspace could be NaN -> must write zeros).
__global__ __launch_bounds__(256, 4) void gather0(
    const float* __restrict__ xinf, const int* __restrict__ row_ptr,
    const int2* __restrict__ csr,
    const float* __restrict__ ew, const float* __restrict__ eb,
    unsigned short* __restrict__ h0) {
    int node = blockIdx.x * 256 + threadIdx.x;
    if (node >= N_NODES) return;  // no barriers below -> early return safe

    float w0 = ew[0], w1 = ew[1], w2 = ew[2], w3 = ew[3], w4 = ew[4];
    float e0 = eb[0], e1 = eb[1], e2 = eb[2], e3 = eb[3], e4 = eb[4];
    const float* xp = xinf + (size_t)node * INDIM;
    float ac0 = xp[0], ac1 = xp[1], ac2 = xp[2], ac3 = xp[3], ac4 = xp[4];

    int beg = row_ptr[node], end = row_ptr[node + 1];
    // 2-deep x pipeline + distance-2 csr prefetch (mirrors gatherH)
    float xa0, xa1, xa2, xa3, xa4, xb0, xb1, xb2, xb3, xb4;
    float aA = 0.f, aB = 0.f;
    int2 rC = make_int2(0, 0), rD = rC, rE = rC, rF = rC;
#define L0X(a, b, c, d, f, src)                      \
    {                                                \
        const float* q_ = xinf + (size_t)(src)*INDIM; \
        a = q_[0]; b = q_[1]; c = q_[2]; d = q_[3]; f = q_[4]; \
    }
#define P0X(a, b, c, d, f, av)                                   \
    {                                                            \
        ac0 += fmaxf(fmaf(av, w0, a + e0), 0.f);                 \
        ac1 += fmaxf(fmaf(av, w1, b + e1), 0.f);                 \
        ac2 += fmaxf(fmaf(av, w2, c + e2), 0.f);                 \
        ac3 += fmaxf(fmaf(av, w3, d + e3), 0.f);                 \
        ac4 += fmaxf(fmaf(av, w4, f + e4), 0.f);                 \
    }
    if (beg < end) {
        int2 r = csr[beg];
        aA = __int_as_float(r.y);
        L0X(xa0, xa1, xa2, xa3, xa4, r.x);
    }
    if (beg + 1 < end) {
        int2 r = csr[beg + 1];
        aB = __int_as_float(r.y);
        L0X(xb0, xb1, xb2, xb3, xb4, r.x);
    }
    if (beg + 2 < end) rC = csr[beg + 2];
    if (beg + 3 < end) rD = csr[beg + 3];
    if (beg + 4 < end) rE = csr[beg + 4];
    if (beg + 5 < end) rF = csr[beg + 5];

    int e = beg;
    while (e + 3 < end) {
        P0X(xa0, xa1, xa2, xa3, xa4, aA);
        L0X(xa0, xa1, xa2, xa3, xa4, rC.x);
        aA = __int_as_float(rC.y);
        P0X(xb0, xb1, xb2, xb3, xb4, aB);
        L0X(xb0, xb1, xb2, xb3, xb4, rD.x);
        aB = __int_as_float(rD.y);
        rC = rE;
        rD = rF;
        int i6 = min(e + 6, end - 1);
        int i7 = min(e + 7, end - 1);
        rE = csr[i6];
        rF = csr[i7];
        e += 2;
    }
    if (e < end) P0X(xa0, xa1, xa2, xa3, xa4, aA);
    if (e + 1 < end) P0X(xb0, xb1, xb2, xb3, xb4, aB);
    if (e + 2 < end) {
        L0X(xa0, xa1, xa2, xa3, xa4, rC.x);
        P0X(xa0, xa1, xa2, xa3, xa4, __int_as_float(rC.y));
    }
#undef L0X
#undef P0X

    unsigned* hp = (unsigned*)(h0 + (size_t)node * 32);
    hp[0] = cvt2_bf(ac0, ac1);
    hp[1] = cvt2_bf(ac2, ac3);
    hp[2] = cvt2_bf(ac4, 0.f);
#pragma unroll
    for (int k = 3; k < 16; ++k) hp[k] = 0;
}

// ---------------- mlpH: stage h -> LDS, then R0-proven wave-local MFMA tail ----------------
// 256 thr = 4 waves x 16 wave-local rows; only barrier: post-stage and pre-epilogue.
template <int KP1, bool POOL>
__global__ __launch_bounds__(256, 4) void mlpH(
    const unsigned short* __restrict__ hin,
    const short* __restrict__ w1h, const float* __restrict__ b1,
    const short* __restrict__ w2h, const float* __restrict__ b2,
    const float* __restrict__ g, const float* __restrict__ bt,
    unsigned short* __restrict__ xout,
    const int* __restrict__ batch, float* __restrict__ pool, int* __restrict__ cnt) {
    __shared__ __align__(16) unsigned short A16[NPBLK * LDA];
    __shared__ int bidx[NPBLK];

    int tid = threadIdx.x;
    int node0 = blockIdx.x * NPBLK;

    // stage-in: contiguous h rows -> A16 (uint2: row byte base 280 is 8B-aligned)
    constexpr int DW2 = KP1 / 4;        // uint2 per row
    constexpr int ITER = NPBLK * DW2 / 256;
#pragma unroll
    for (int i = 0; i < ITER; ++i) {
        int idx = tid + 256 * i;
        int row = idx / DW2, w2 = idx % DW2;
        ((uint2*)&A16[row * LDA])[w2] =
            ((const uint2*)(hin + (size_t)(node0 + row) * KP1))[w2];
    }
    if (POOL && tid >= 64 && tid < 128) bidx[tid - 64] = batch[node0 + tid - 64];
    __syncthreads();

    // ---- R0-proven tail: wave-local 16 rows, 8 column tiles ----
    int wv = tid >> 6, lane = tid & 63;
    int mrow = lane & 15, q = lane >> 4;
    int arow = wv * 16 + mrow;

    const short8* w1p = (const short8*)w1h;
    const short8* w2p = (const short8*)w2h;

    f32x4 acc2[8];
#pragma unroll
    for (int t = 0; t < 8; ++t) acc2[t] = (f32x4){0.f, 0.f, 0.f, 0.f};
    constexpr int KS1 = KP1 / 32;
#pragma unroll
    for (int ks = 0; ks < KS1; ++ks) {
        short8 bh[8];
#pragma unroll
        for (int t = 0; t < 8; ++t) bh[t] = w1p[((size_t)t * KS1 + ks) * 64 + lane];
        short8 ah = *(const short8*)&A16[arow * LDA + ks * 32 + q * 8];
#pragma unroll
        for (int t = 0; t < 8; ++t)
            acc2[t] = __builtin_amdgcn_mfma_f32_16x16x32_bf16(ah, bh[t], acc2[t], 0, 0, 0);
    }
    // t1 = relu(acc + b1) -> bf16 A (wave-local rows; no barrier)
    {
        float b1v[8];
#pragma unroll
        for (int t = 0; t < 8; ++t) b1v[t] = b1[t * 16 + mrow];
#pragma unroll
        for (int t = 0; t < 8; ++t)
#pragma unroll
            for (int r = 0; r < 4; ++r) {
                int rrow = wv * 16 + q * 4 + r;
                int col = t * 16 + mrow;
                A16[rrow * LDA + col] = cvt1_bf(fmaxf(acc2[t][r] + b1v[t], 0.f));
            }
    }

    // GEMM2 (K = 128); wave-local A reads
#pragma unroll
    for (int t = 0; t < 8; ++t) acc2[t] = (f32x4){0.f, 0.f, 0.f, 0.f};
#pragma unroll
    for (int ks = 0; ks < 4; ++ks) {
        short8 bh[8];
#pragma unroll
        for (int t = 0; t < 8; ++t) bh[t] = w2p[((size_t)t * 4 + ks) * 64 + lane];
        short8 ah = *(const short8*)&A16[arow * LDA + ks * 32 + q * 8];
#pragma unroll
        for (int t = 0; t < 8; ++t)
            acc2[t] = __builtin_amdgcn_mfma_f32_16x16x32_bf16(ah, bh[t], acc2[t], 0, 0, 0);
    }

    // LayerNorm in registers (full 128-col rows within the wave)
    float s4[4] = {0.f, 0.f, 0.f, 0.f}, q4[4] = {0.f, 0.f, 0.f, 0.f};
    {
        float b2v[8];
#pragma unroll
        for (int t = 0; t < 8; ++t) b2v[t] = b2[t * 16 + mrow];
#pragma unroll
        for (int t = 0; t < 8; ++t)
#pragma unroll
            for (int r = 0; r < 4; ++r) {
                float v = acc2[t][r] + b2v[t];
                acc2[t][r] = v;
                s4[r] += v;
                q4[r] += v * v;
            }
    }
#pragma unroll
    for (int m = 1; m <= 8; m <<= 1) {
#pragma unroll
        for (int r = 0; r < 4; ++r) {
            s4[r] += __shfl_xor(s4[r], m, 64);
            q4[r] += __shfl_xor(q4[r], m, 64);
        }
    }
    float mu[4], inv[4];
#pragma unroll
    for (int r = 0; r < 4; ++r) {
        mu[r] = s4[r] * (1.f / HDIM);
        float var = q4[r] * (1.f / HDIM) - mu[r] * mu[r];
        inv[r] = rsqrtf(var + LN_EPS);
    }
    float gv[8], btv[8];
#pragma unroll
    for (int t = 0; t < 8; ++t) {
        gv[t] = g[t * 16 + mrow];
        btv[t] = bt[t * 16 + mrow];
    }

#pragma unroll
    for (int t = 0; t < 8; ++t)
#pragma unroll
        for (int r = 0; r < 4; ++r) {
            int rrow = wv * 16 + q * 4 + r;
            int col = t * 16 + mrow;
            float o = fmaxf((acc2[t][r] - mu[r]) * inv[r] * gv[t] + btv[t], 0.f);
            A16[rrow * LDA + col] = cvt1_bf(o);
        }
    __syncthreads();  // epilogue reads all rows (cross-wave)

    if (!POOL) {
        unsigned* xo = (unsigned*)xout;
#pragma unroll
        for (int i = 0; i < 16; ++i) {
            int idx = tid + 256 * i;  // 4096 = 64 rows x 64 dwords
            int row = idx >> 6, w = idx & 63;
            xo[(size_t)(node0 + row) * 64 + w] = ((const unsigned*)&A16[row * LDA])[w];
        }
    } else {
        if (tid < 128) {
            int col = tid;
            float accp = 0.f;
            int cur = bidx[0];
            for (int r = 0; r < NPBLK; ++r) {
                int gi = bidx[r];
                if (gi != cur) {
                    unsafeAtomicAdd(&pool[cur * HDIM + col], accp);
                    accp = 0.f;
                    cur = gi;
                }
                accp += bf2f(A16[r * LDA + col]);
            }
            unsafeAtomicAdd(&pool[cur * HDIM + col], accp);
        } else if (tid == 255) {
            int cur = bidx[0], c = 0;
            for (int r = 0; r < NPBLK; ++r) {
                if (bidx[r] != cur) {
                    atomicAdd(&cnt[cur], c);
                    c = 0;
                    cur = bidx[r];
                }
                ++c;
            }
            atomicAdd(&cnt[cur], c);
        }
    }
}

__global__ void pool_final(const float* __restrict__ pool, const int* __restrict__ cnt,
                           float* __restrict__ out) {
    int g = blockIdx.x, j = threadIdx.x;
    float add = pool[g * HDIM + j];
    float c = (float)max(cnt[g], 1);
    out[g * (2 * HDIM) + j] = add / c;
    out[g * (2 * HDIM) + HDIM + j] = add;
}

extern "C" void kernel_launch(void* const* d_in, const int* in_sizes, int n_in,
                              void* d_out, int out_size, void* d_ws, size_t ws_size,
                              hipStream_t stream) {
    const float* x_in = (const float*)d_in[0];
    const int* ei = (const int*)d_in[1];
    const float* ea = (const float*)d_in[2];
    const int* batch = (const int*)d_in[3];
    const float* P[24];
    for (int i = 0; i < 24; ++i) P[i] = (const float*)d_in[4 + i];
    // per layer l (base 8l): 0=ew 1=eb 2=w1 3=b1 4=w2 5=b2 6=g 7=bt

    unsigned short* x_a = (unsigned short*)d_ws;                 // N*128 bf16
    unsigned short* x_b = x_a + (size_t)N_NODES * HDIM;          // N*128 bf16
    unsigned short* hbuf = x_b + (size_t)N_NODES * HDIM;         // N*128 bf16 (h0 aliases start)
    unsigned short* h0 = hbuf;                                   // N*32 bf16 (dead before G1 writes hbuf)
    float* pool = (float*)(hbuf + (size_t)N_NODES * HDIM);       // G*128 (zeroed in scanA)
    int* cnt = (int*)(pool + N_GRAPHS * HDIM);                   // G    (zeroed in scanA)
    int* deg = cnt + N_GRAPHS;                                   // N    (memset)
    int* cursor = deg + N_NODES;                                 // N    (zeroed in scanC)
    int* row_ptr = cursor + N_NODES;                             // N+1
    int* bsums = row_ptr + N_NODES + 1;                          // pad 256 (keeps int2 8B-aligned)
    int2* csr = (int2*)(bsums + 256);                            // E (packed {src, val})
    short* wp = (short*)(((uintptr_t)(csr + N_EDGES) + 15) & ~(uintptr_t)15);
    float* out = (float*)d_out;

    short *w1h[3], *w2h[3];
    for (int l = 0; l < 3; ++l) {
        w1h[l] = wp + (size_t)l * 32768;
        w2h[l] = w1h[l] + 16384;
    }

    // ---- memset: deg only (pool/cnt zeroed in scanA, cursor in scanC) ----
    hipMemsetAsync(deg, 0, N_NODES * sizeof(int), stream);

    // ---- CSR build ----
    hist_kernel<<<(N_EDGES + 255) / 256, 256, 0, stream>>>(ei, deg);
    scan_phaseA<<<SCAN_BLOCKS, 256, 0, stream>>>(deg, bsums, (int*)pool);
    scan_phaseB<<<1, 256, 0, stream>>>(bsums, row_ptr);
    scan_phaseC<<<SCAN_BLOCKS, 256, 0, stream>>>(deg, bsums, row_ptr, cursor);

    // ---- fused scatter + weight packing ----
    scatter_pack<<<SCATTER_BLOCKS + 336, 256, 0, stream>>>(
        ei, ea, row_ptr, cursor, csr,
        P[2], w1h[0], P[4], w2h[0],
        P[10], w1h[1], P[12], w2h[1],
        P[18], w1h[2], P[20], w2h[2]);

    // ---- layer 0: gather (din=5) -> MLP ----
    gather0<<<(N_NODES + 255) / 256, 256, 0, stream>>>(x_in, row_ptr, csr, P[0], P[1], h0);
    mlpH<32, false><<<N_NODES / NPBLK, 256, 0, stream>>>(
        h0, w1h[0], P[3], w2h[0], P[5], P[6], P[7], x_a, nullptr, nullptr, nullptr);

    // ---- layer 1 ----
    gatherH<<<N_NODES / GROWS, 256, 0, stream>>>(x_a, row_ptr, csr, P[8], P[9], hbuf);
    mlpH<128, false><<<N_NODES / NPBLK, 256, 0, stream>>>(
        hbuf, w1h[1], P[11], w2h[1], P[13], P[14], P[15], x_b, nullptr, nullptr, nullptr);

    // ---- layer 2 (+pool) ----
    gatherH<<<N_NODES / GROWS, 256, 0, stream>>>(x_b, row_ptr, csr, P[16], P[17], hbuf);
    mlpH<128, true><<<N_NODES / NPBLK, 256, 0, stream>>>(
        hbuf, w1h[2], P[19], w2h[2], P[21], P[22], P[23], nullptr, batch, pool, cnt);

    pool_final<<<N_GRAPHS, HDIM, 0, stream>>>(pool, cnt, out);
}

// Round 8
// 341.925 us; speedup vs baseline: 1.7537x; 1.1166x over previous
//
#include <hip/hip_runtime.h>

#define N_NODES 200000
#define N_EDGES 400000
#define N_GRAPHS 64
#define HDIM 128
#define INDIM 5
#define LN_EPS 1e-5f
#define LDA 140  // 70 dwords/row: 70 mod 32 = 6 -> frag reads distributed; 2-way-only write aliasing
#define NPBLK 64 // nodes per block (4 waves x 16 wave-local rows -- R0-proven config)

typedef __attribute__((ext_vector_type(8))) short short8;
typedef __attribute__((ext_vector_type(4))) float f32x4;
typedef __attribute__((ext_vector_type(2))) float f32x2;

__device__ __forceinline__ unsigned short to_bf(float v) {
    unsigned u = __builtin_bit_cast(unsigned, v);
    return (unsigned short)((u + 0x7FFFu + ((u >> 16) & 1u)) >> 16);
}
__device__ __forceinline__ float bf_lo(unsigned w) { return __builtin_bit_cast(float, w << 16); }
__device__ __forceinline__ float bf_hi(unsigned w) { return __builtin_bit_cast(float, w & 0xFFFF0000u); }
__device__ __forceinline__ float bf2f(unsigned short h) { return __builtin_bit_cast(float, (unsigned)h << 16); }

// 1-instr RTNE f32->bf16 (same rounding as to_bf)
__device__ __forceinline__ unsigned short cvt1_bf(float v) {
    unsigned r;
    asm("v_cvt_pk_bf16_f32 %0, %1, %1" : "=v"(r) : "v"(v));
    return (unsigned short)r;
}
__device__ __forceinline__ unsigned cvt2_bf(float lo, float hi) {
    unsigned r;
    asm("v_cvt_pk_bf16_f32 %0, %1, %2" : "=v"(r) : "v"(lo), "v"(hi));
    return r;
}
__device__ __forceinline__ f32x2 vmax0(f32x2 v) {
#if __has_builtin(__builtin_elementwise_max)
    return __builtin_elementwise_max(v, (f32x2)0.f);
#else
    v.x = fmaxf(v.x, 0.f);
    v.y = fmaxf(v.y, 0.f);
    return v;
#endif
}

// ---- gather macros: 32 ch/thread (16 dwords = 4 uint4). Literal indices only,
// no staging arrays, no pointer-passed locals (R1/R3 lessons), no token pasting (R2).
#define GLOAD(p0, p1, p2, p3, srcrow)                                       \
    {                                                                       \
        const uint4* xs_ = (const uint4*)(xin + (size_t)(srcrow)*128 + c0); \
        p0 = xs_[0]; p1 = xs_[1]; p2 = xs_[2]; p3 = xs_[3];                 \
    }

// one dword wd = channel pair (2*i0, 2*i0+1): accv += relu((x + eb) + a*ew), packed f32x2
#define GP2(wd, i0)            \
    {                          \
        float4 wb_ = ep[i0];   \
        f32x2 xv_;             \
        xv_.x = bf_lo(wd);     \
        xv_.y = bf_hi(wd);     \
        f32x2 ew_, eb_;        \
        ew_.x = wb_.x;         \
        ew_.y = wb_.y;         \
        eb_.x = wb_.z;         \
        eb_.y = wb_.w;         \
        f32x2 t_ = xv_ + eb_;  \
        t_ = av2_ * ew_ + t_;  \
        accv[i0] += vmax0(t_); \
    }

#define GPROC(p0, p1, p2, p3, a_)                               \
    {                                                           \
        f32x2 av2_;                                             \
        av2_.x = (a_);                                          \
        av2_.y = (a_);                                          \
        GP2(p0.x, 0) GP2(p0.y, 1) GP2(p0.z, 2) GP2(p0.w, 3)     \
        GP2(p1.x, 4) GP2(p1.y, 5) GP2(p1.z, 6) GP2(p1.w, 7)     \
        GP2(p2.x, 8) GP2(p2.y, 9) GP2(p2.z, 10) GP2(p2.w, 11)   \
        GP2(p3.x, 12) GP2(p3.y, 13) GP2(p3.z, 14) GP2(p3.w, 15) \
    }

#define GI2(wd, i0)             \
    {                           \
        accv[i0].x = bf_lo(wd); \
        accv[i0].y = bf_hi(wd); \
    }

#define GINIT(p0, p1, p2, p3)                                   \
    {                                                           \
        GI2(p0.x, 0) GI2(p0.y, 1) GI2(p0.z, 2) GI2(p0.w, 3)     \
        GI2(p1.x, 4) GI2(p1.y, 5) GI2(p1.z, 6) GI2(p1.w, 7)     \
        GI2(p2.x, 8) GI2(p2.y, 9) GI2(p2.z, 10) GI2(p2.w, 11)   \
        GI2(p3.x, 12) GI2(p3.y, 13) GI2(p3.z, 14) GI2(p3.w, 15) \
    }

// ---------------- CSR build ----------------

__global__ void hist_kernel(const int* __restrict__ ei, int* __restrict__ deg) {
    int e = blockIdx.x * blockDim.x + threadIdx.x;
    if (e < N_EDGES) atomicAdd(&deg[ei[N_EDGES + e]], 1);
}

#define SCAN_CHUNK 1024
#define SCAN_BLOCKS ((N_NODES + SCAN_CHUNK - 1) / SCAN_CHUNK)  // 196

__global__ __launch_bounds__(256) void scan_phaseA(const int* __restrict__ deg, int* __restrict__ bsums,
                                                   int* __restrict__ poolz) {
    if (blockIdx.x == 0) {
        for (int i = threadIdx.x; i < N_GRAPHS * HDIM + N_GRAPHS; i += 256) poolz[i] = 0;
    }
    __shared__ int red[256];
    int t = threadIdx.x;
    int base = blockIdx.x * SCAN_CHUNK + t * 4;
    int s = 0;
#pragma unroll
    for (int k = 0; k < 4; ++k) {
        int i = base + k;
        s += (i < N_NODES) ? deg[i] : 0;
    }
    red[t] = s;
    __syncthreads();
    for (int off = 128; off; off >>= 1) {
        if (t < off) red[t] += red[t + off];
        __syncthreads();
    }
    if (t == 0) bsums[blockIdx.x] = red[0];
}

__global__ __launch_bounds__(256) void scan_phaseB(int* __restrict__ bsums, int* __restrict__ row_ptr) {
    __shared__ int s[256];
    int t = threadIdx.x;
    int v = (t < SCAN_BLOCKS) ? bsums[t] : 0;
    s[t] = v;
    __syncthreads();
    for (int off = 1; off < 256; off <<= 1) {
        int add = (t >= off) ? s[t - off] : 0;
        __syncthreads();
        s[t] += add;
        __syncthreads();
    }
    if (t < SCAN_BLOCKS) bsums[t] = s[t] - v;  // exclusive
    if (t == SCAN_BLOCKS - 1) row_ptr[N_NODES] = s[t];
}

__global__ __launch_bounds__(256) void scan_phaseC(const int* __restrict__ deg,
                                                   const int* __restrict__ bsums,
                                                   int* __restrict__ row_ptr,
                                                   int* __restrict__ cursor) {
    __shared__ int ts[256];
    int t = threadIdx.x;
    int base = blockIdx.x * SCAN_CHUNK + t * 4;
    int v[4];
    int s = 0;
#pragma unroll
    for (int k = 0; k < 4; ++k) {
        int i = base + k;
        v[k] = (i < N_NODES) ? deg[i] : 0;
        s += v[k];
    }
    ts[t] = s;
    __syncthreads();
    for (int off = 1; off < 256; off <<= 1) {
        int add = (t >= off) ? ts[t - off] : 0;
        __syncthreads();
        ts[t] += add;
        __syncthreads();
    }
    int run = bsums[blockIdx.x] + ts[t] - s;
#pragma unroll
    for (int k = 0; k < 4; ++k) {
        int i = base + k;
        if (i < N_NODES) { row_ptr[i] = run; cursor[i] = 0; }
        run += v[k];
    }
}

// ---------------- Fused scatter (CSR fill) + weight packing ----------------
#define SCATTER_BLOCKS ((N_EDGES + 255) / 256)  // 1563

__global__ void scatter_pack(const int* __restrict__ ei, const float* __restrict__ ea,
                             const int* __restrict__ row_ptr, int* __restrict__ cursor,
                             int2* __restrict__ csr,
                             const float* __restrict__ s0, short* __restrict__ d0,
                             const float* __restrict__ s1, short* __restrict__ d1,
                             const float* __restrict__ s2, short* __restrict__ d2,
                             const float* __restrict__ s3, short* __restrict__ d3,
                             const float* __restrict__ s4, short* __restrict__ d4,
                             const float* __restrict__ s5, short* __restrict__ d5) {
    int b = blockIdx.x;
    if (b < SCATTER_BLOCKS) {
        int e = b * 256 + threadIdx.x;
        if (e >= N_EDGES) return;
        int d = ei[N_EDGES + e];
        int pos = atomicAdd(&cursor[d], 1);
        csr[row_ptr[d] + pos] = make_int2(ei[e], __float_as_int(ea[e]));
        return;
    }
    b -= SCATTER_BLOCKS;
    const float* W;
    short* D;
    int din, KP, b0;
    if (b < 16)       { W = s0; D = d0; din = 5;   KP = 32;  b0 = 0; }
    else if (b < 80)  { W = s1; D = d1; din = 128; KP = 128; b0 = 16; }
    else if (b < 144) { W = s2; D = d2; din = 128; KP = 128; b0 = 80; }
    else if (b < 208) { W = s3; D = d3; din = 128; KP = 128; b0 = 144; }
    else if (b < 272) { W = s4; D = d4; din = 128; KP = 128; b0 = 208; }
    else              { W = s5; D = d5; din = 128; KP = 128; b0 = 272; }
    int idx = (b - b0) * 256 + threadIdx.x;
    if (idx >= KP * 128) return;
    int j = idx & 7;
    int lane = (idx >> 3) & 63;
    int rest = idx >> 9;
    int KS = KP >> 5;
    int kstep = rest % KS;
    int tile = rest / KS;
    int k = kstep * 32 + ((lane >> 4) * 8) + j;
    int n = tile * 16 + (lane & 15);
    float v = (k < din) ? W[k * 128 + n] : 0.f;
    D[idx] = (short)to_bf(v);
}

// ---------------- Fused layer: gather + MFMA MLP + reg-LN + ReLU (+pool) ----------------
// R0-proven structure: 256 thr = 4 waves, 64 nodes/block, wave-local tail (16 rows/wave,
// no cross-wave barrier between gather and tail). (256,4): allocator targets 64 VGPR;
// gather live set ~60 (accv 32 + 1-deep buf 16 + csr prefetch 4 + addr) -> no spill.
template <int KP1, bool POOL>
__global__ __launch_bounds__(256, 4) void layer_fused(
    const void* __restrict__ xin_v, const int* __restrict__ row_ptr,
    const int2* __restrict__ csr,
    const float* __restrict__ ew, const float* __restrict__ eb,
    const short* __restrict__ w1h, const float* __restrict__ b1,
    const short* __restrict__ w2h, const float* __restrict__ b2,
    const float* __restrict__ g, const float* __restrict__ bt,
    unsigned short* __restrict__ xout,
    const int* __restrict__ batch, float* __restrict__ pool, int* __restrict__ cnt) {
    __shared__ __align__(16) unsigned short A16[NPBLK * LDA];
    __shared__ int bidx[NPBLK];
    union Scratch {
        float4 eweb4[4 * 17];                          // {ew,ew,eb,eb} pairs, qt-stride 17 (conflict-free)
        float part[KP1 == 128 ? 1 : NPBLK][4][INDIM];  // layer-0 gather partials
    };
    __shared__ __align__(16) Scratch u;

    int tid = threadIdx.x;
    int node0 = blockIdx.x * NPBLK;

    if constexpr (KP1 == 128) {
        const unsigned short* xin = (const unsigned short*)xin_v;
        // stage padded edge-encoder table (conflict-free broadcast reads: qt groups 4 banks apart)
        if (tid < 64) {
            int qq = tid >> 4, ii = tid & 15, c = qq * 32 + ii * 2;
            u.eweb4[qq * 17 + ii] = make_float4(ew[c], ew[c + 1], eb[c], eb[c + 1]);
        }
        if (POOL && tid >= 64 && tid < 128) bidx[tid - 64] = batch[node0 + tid - 64];

        // thread = (row, 32-channel quarter)
        int row = tid >> 2, qt = tid & 3, c0 = qt * 32;
        int node = node0 + row;

        // own-row + pipeline prologue issued before the barrier (in flight across it)
        const uint4* xn = (const uint4*)(xin + (size_t)node * 128 + c0);
        uint4 o0 = xn[0], o1 = xn[1], o2 = xn[2], o3 = xn[3];
        int beg = row_ptr[node], end = row_ptr[node + 1];

        uint4 va0, va1, va2, va3;
        float aA = 0.f;
        int2 rC = make_int2(0, 0), rD = rC;
        if (beg < end) {
            int2 r = csr[beg];
            aA = __int_as_float(r.y);
            GLOAD(va0, va1, va2, va3, r.x);
        }
        if (beg + 1 < end) rC = csr[beg + 1];
        if (beg + 2 < end) rD = csr[beg + 2];
        __syncthreads();  // eweb4 ready
        const float4* ep = u.eweb4 + qt * 17;

        f32x2 accv[16];
        GINIT(o0, o1, o2, o3);

        // 1-deep x pipeline + distance-2 csr prefetch (R6-proven codegen):
        // record for edge e+1 is RESIDENT when its GLOAD issues; csr never on the chain.
        int e = beg;
        while (e + 1 < end) {
            GPROC(va0, va1, va2, va3, aA);   // waits on this edge's x only
            aA = __int_as_float(rC.y);
            GLOAD(va0, va1, va2, va3, rC.x); // rC resident -> issue immediately
            rC = rD;                         // rD in flight since last iter (cheap partial wait)
            int i3 = min(e + 3, end - 1);    // unconditional clamped (no branch-merge waitcnt)
            rD = csr[i3];
            ++e;
        }
        if (e < end) GPROC(va0, va1, va2, va3, aA);

        // packed cvt + uint2 stores (2-way bank aliasing only = free)
        uint2* Ar2 = (uint2*)&A16[row * LDA + c0];
#pragma unroll
        for (int k = 0; k < 8; ++k) {
            Ar2[k] = make_uint2(cvt2_bf(accv[2 * k].x, accv[2 * k].y),
                                cvt2_bf(accv[2 * k + 1].x, accv[2 * k + 1].y));
        }
        // no barrier: rows [16wv,16wv+16) are written and read by the same wave
    } else {
        // layer 0 (din=5): 4 threads/row split the edge list; register partials
        const float* xinf = (const float*)xin_v;
        int row = tid >> 2, qt = tid & 3;
        int node = node0 + row;
        {
            float w[INDIM], b[INDIM], acc[INDIM];
#pragma unroll
            for (int j = 0; j < INDIM; ++j) {
                w[j] = ew[j];
                b[j] = eb[j];
                acc[j] = 0.f;
            }
            int beg = row_ptr[node], end = row_ptr[node + 1];
            int2 r;
            if (beg + qt < end) r = csr[beg + qt];
            for (int e = beg + qt; e < end; e += 4) {
                int2 rn = (e + 4 < end) ? csr[e + 4] : r;
                float a = __int_as_float(r.y);
#pragma unroll
                for (int j = 0; j < INDIM; ++j)
                    acc[j] += fmaxf(fmaf(a, w[j], xinf[r.x * INDIM + j] + b[j]), 0.f);
                r = rn;
            }
#pragma unroll
            for (int j = 0; j < INDIM; ++j) u.part[row][qt][j] = acc[j];
        }
        __syncthreads();
        if (tid < NPBLK) {
#pragma unroll
            for (int j = 0; j < INDIM; ++j) {
                float v = xinf[(node0 + tid) * INDIM + j] + u.part[tid][0][j] + u.part[tid][1][j] +
                          u.part[tid][2][j] + u.part[tid][3][j];
                A16[tid * LDA + j] = cvt1_bf(v);
            }
#pragma unroll
            for (int j = INDIM; j < 32; ++j) A16[tid * LDA + j] = 0;
        }
        __syncthreads();  // rows written by tid<64 -> cross-wave
    }

    // ---- MFMA MLP (wave-local rows) ----
    int wv = tid >> 6, lane = tid & 63;
    int mrow = lane & 15, q = lane >> 4;
    int arow = wv * 16 + mrow;

    const short8* w1p = (const short8*)w1h;
    const short8* w2p = (const short8*)w2h;

    f32x4 acc2[8];
#pragma unroll
    for (int t = 0; t < 8; ++t) acc2[t] = (f32x4){0.f, 0.f, 0.f, 0.f};
    constexpr int KS1 = KP1 / 32;
#pragma unroll
    for (int ks = 0; ks < KS1; ++ks) {
        short8 bh[8];
#pragma unroll
        for (int t = 0; t < 8; ++t) bh[t] = w1p[((size_t)t * KS1 + ks) * 64 + lane];
        short8 ah = *(const short8*)&A16[arow * LDA + ks * 32 + q * 8];
#pragma unroll
        for (int t = 0; t < 8; ++t)
            acc2[t] = __builtin_amdgcn_mfma_f32_16x16x32_bf16(ah, bh[t], acc2[t], 0, 0, 0);
    }
    // t1 = relu(acc + b1) -> bf16 A (wave-local rows)
    {
        float b1v[8];
#pragma unroll
        for (int t = 0; t < 8; ++t) b1v[t] = b1[t * 16 + mrow];
#pragma unroll
        for (int t = 0; t < 8; ++t)
#pragma unroll
            for (int r = 0; r < 4; ++r) {
                int rrow = wv * 16 + q * 4 + r;
                int col = t * 16 + mrow;
                A16[rrow * LDA + col] = cvt1_bf(fmaxf(acc2[t][r] + b1v[t], 0.f));
            }
    }

    // GEMM2 (K = 128); A reads wave-local
#pragma unroll
    for (int t = 0; t < 8; ++t) acc2[t] = (f32x4){0.f, 0.f, 0.f, 0.f};
#pragma unroll
    for (int ks = 0; ks < 4; ++ks) {
        short8 bh[8];
#pragma unroll
        for (int t = 0; t < 8; ++t) bh[t] = w2p[((size_t)t * 4 + ks) * 64 + lane];
        short8 ah = *(const short8*)&A16[arow * LDA + ks * 32 + q * 8];
#pragma unroll
        for (int t = 0; t < 8; ++t)
            acc2[t] = __builtin_amdgcn_mfma_f32_16x16x32_bf16(ah, bh[t], acc2[t], 0, 0, 0);
    }

    // ---- LayerNorm in registers (rows live in 16-lane groups) ----
    float s4[4] = {0.f, 0.f, 0.f, 0.f}, q4[4] = {0.f, 0.f, 0.f, 0.f};
    {
        float b2v[8];
#pragma unroll
        for (int t = 0; t < 8; ++t) b2v[t] = b2[t * 16 + mrow];
#pragma unroll
        for (int t = 0; t < 8; ++t)
#pragma unroll
            for (int r = 0; r < 4; ++r) {
                float v = acc2[t][r] + b2v[t];
                acc2[t][r] = v;
                s4[r] += v;
                q4[r] += v * v;
            }
    }
#pragma unroll
    for (int m = 1; m <= 8; m <<= 1) {
#pragma unroll
        for (int r = 0; r < 4; ++r) {
            s4[r] += __shfl_xor(s4[r], m, 64);
            q4[r] += __shfl_xor(q4[r], m, 64);
        }
    }
    float mu[4], inv[4];
#pragma unroll
    for (int r = 0; r < 4; ++r) {
        mu[r] = s4[r] * (1.f / HDIM);
        float var = q4[r] * (1.f / HDIM) - mu[r] * mu[r];
        inv[r] = rsqrtf(var + LN_EPS);
    }
    float gv[8], btv[8];
#pragma unroll
    for (int t = 0; t < 8; ++t) {
        gv[t] = g[t * 16 + mrow];
        btv[t] = bt[t * 16 + mrow];
    }

    // LN result -> LDS (wave-local row writes; no pre-barrier needed)
#pragma unroll
    for (int t = 0; t < 8; ++t)
#pragma unroll
        for (int r = 0; r < 4; ++r) {
            int rrow = wv * 16 + q * 4 + r;
            int col = t * 16 + mrow;
            float o = fmaxf((acc2[t][r] - mu[r]) * inv[r] * gv[t] + btv[t], 0.f);
            A16[rrow * LDA + col] = cvt1_bf(o);
        }
    __syncthreads();  // epilogue reads all rows (cross-wave)

    if (!POOL) {
        // coalesced copy-out: wave inst covers 256 contiguous bytes (4 full lines)
        unsigned* xo = (unsigned*)xout;
#pragma unroll
        for (int i = 0; i < 16; ++i) {
            int idx = tid + 256 * i;       // 4096 = 64 rows x 64 words
            int row = idx >> 6, w = idx & 63;
            xo[(size_t)(node0 + row) * 64 + w] = ((const unsigned*)&A16[row * LDA])[w];
        }
    } else {
        if (tid < 128) {
            int col = tid;
            float accp = 0.f;
            int cur = bidx[0];
            for (int r = 0; r < NPBLK; ++r) {
                int gi = bidx[r];
                if (gi != cur) {
                    unsafeAtomicAdd(&pool[cur * HDIM + col], accp);
                    accp = 0.f;
                    cur = gi;
                }
                accp += bf2f(A16[r * LDA + col]);
            }
            unsafeAtomicAdd(&pool[cur * HDIM + col], accp);
        } else if (tid == 255) {
            int cur = bidx[0], c = 0;
            for (int r = 0; r < NPBLK; ++r) {
                if (bidx[r] != cur) {
                    atomicAdd(&cnt[cur], c);
                    c = 0;
                    cur = bidx[r];
                }
                ++c;
            }
            atomicAdd(&cnt[cur], c);
        }
    }
}

__global__ void pool_final(const float* __restrict__ pool, const int* __restrict__ cnt,
                           float* __restrict__ out) {
    int g = blockIdx.x, j = threadIdx.x;
    float add = pool[g * HDIM + j];
    float c = (float)max(cnt[g], 1);
    out[g * (2 * HDIM) + j] = add / c;
    out[g * (2 * HDIM) + HDIM + j] = add;
}

extern "C" void kernel_launch(void* const* d_in, const int* in_sizes, int n_in,
                              void* d_out, int out_size, void* d_ws, size_t ws_size,
                              hipStream_t stream) {
    const float* x_in = (const float*)d_in[0];
    const int* ei = (const int*)d_in[1];
    const float* ea = (const float*)d_in[2];
    const int* batch = (const int*)d_in[3];
    const float* P[24];
    for (int i = 0; i < 24; ++i) P[i] = (const float*)d_in[4 + i];
    // per layer l (base 8l): 0=ew 1=eb 2=w1 3=b1 4=w2 5=b2 6=g 7=bt

    unsigned short* x_a = (unsigned short*)d_ws;                 // N*128 bf16
    unsigned short* x_b = x_a + (size_t)N_NODES * HDIM;          // N*128 bf16
    float* pool = (float*)(x_b + (size_t)N_NODES * HDIM);        // G*128 (zeroed in scanA)
    int* cnt = (int*)(pool + N_GRAPHS * HDIM);                   // G    (zeroed in scanA)
    int* deg = cnt + N_GRAPHS;                                   // N    (memset)
    int* cursor = deg + N_NODES;                                 // N    (zeroed in scanC)
    int* row_ptr = cursor + N_NODES;                             // N+1
    int* bsums = row_ptr + N_NODES + 1;                          // pad 256 (keeps int2 8B-aligned)
    int2* csr = (int2*)(bsums + 256);                            // E (packed {src, val})
    short* wp = (short*)(((uintptr_t)(csr + N_EDGES) + 15) & ~(uintptr_t)15);
    float* out = (float*)d_out;

    short *w1h[3], *w2h[3];
    for (int l = 0; l < 3; ++l) {
        w1h[l] = wp + (size_t)l * 32768;
        w2h[l] = w1h[l] + 16384;
    }

    // ---- memset: deg only (pool/cnt zeroed in scanA, cursor in scanC) ----
    hipMemsetAsync(deg, 0, N_NODES * sizeof(int), stream);

    // ---- CSR build ----
    hist_kernel<<<(N_EDGES + 255) / 256, 256, 0, stream>>>(ei, deg);
    scan_phaseA<<<SCAN_BLOCKS, 256, 0, stream>>>(deg, bsums, (int*)pool);
    scan_phaseB<<<1, 256, 0, stream>>>(bsums, row_ptr);
    scan_phaseC<<<SCAN_BLOCKS, 256, 0, stream>>>(deg, bsums, row_ptr, cursor);

    // ---- fused scatter + weight packing (1563 + 336 blocks) ----
    scatter_pack<<<SCATTER_BLOCKS + 336, 256, 0, stream>>>(
        ei, ea, row_ptr, cursor, csr,
        P[2], w1h[0], P[4], w2h[0],
        P[10], w1h[1], P[12], w2h[1],
        P[18], w1h[2], P[20], w2h[2]);

    // ---- fused layers ----
    layer_fused<32, false><<<N_NODES / NPBLK, 256, 0, stream>>>(
        x_in, row_ptr, csr, P[0], P[1],
        w1h[0], P[3], w2h[0], P[5], P[6], P[7], x_a, nullptr, nullptr, nullptr);
    layer_fused<128, false><<<N_NODES / NPBLK, 256, 0, stream>>>(
        x_a, row_ptr, csr, P[8], P[9],
        w1h[1], P[11], w2h[1], P[13], P[14], P[15], x_b, nullptr, nullptr, nullptr);
    layer_fused<128, true><<<N_NODES / NPBLK, 256, 0, stream>>>(
        x_b, row_ptr, csr, P[16], P[17],
        w1h[2], P[19], w2h[2], P[21], P[22], P[23], nullptr, batch, pool, cnt);

    pool_final<<<N_GRAPHS, HDIM, 0, stream>>>(pool, cnt, out);
}